// Round 8
// baseline (340.215 us; speedup 1.0000x reference)
//
#include <hip/hip_runtime.h>
#include <math.h>

#define Bc 2
#define Sc 2048
#define Dc 1024
#define Hc 16
#define HDc 64
#define NROWS 4096  // B*S

typedef __attribute__((ext_vector_type(8))) _Float16 f16x8;
typedef __attribute__((ext_vector_type(4))) _Float16 f16x4;
typedef __attribute__((ext_vector_type(2))) __fp16 fp16v2;
typedef __attribute__((ext_vector_type(4))) float f32x4;

// ---------------------------------------------------------------------------
// fp32 -> f16 hi + f16 lo  (x = hi + lo, lo = x - (float)hi)
// ---------------------------------------------------------------------------
__global__ __launch_bounds__(256)
void split_kernel(const float* __restrict__ src, _Float16* __restrict__ hi,
                  _Float16* __restrict__ lo, int n4)
{
  int i = blockIdx.x * 256 + threadIdx.x;
  if (i >= n4) return;
  float4 v = reinterpret_cast<const float4*>(src)[i];
  f16x4 h, l;
  h[0] = (_Float16)v.x; l[0] = (_Float16)(v.x - (float)h[0]);
  h[1] = (_Float16)v.y; l[1] = (_Float16)(v.y - (float)h[1]);
  h[2] = (_Float16)v.z; l[2] = (_Float16)(v.z - (float)h[2]);
  h[3] = (_Float16)v.w; l[3] = (_Float16)(v.w - (float)h[3]);
  reinterpret_cast<f16x4*>(hi)[i] = h;
  reinterpret_cast<f16x4*>(lo)[i] = l;
}

// ---------------------------------------------------------------------------
// Split-precision MFMA GEMM: C = (A@W^T + bias)*alpha via f16 hi/lo (3 MFMA).
//   mode 0: f16 head-split -> outb [B,H,S,HD]            (rows=B*S, cols=D)
//   mode 1: f16, rows are the o-index -> outb [B,H,HD,S] (rows=D, cols=B*S)
//           (bias indexed by ROW)
//   mode 2: fp32: out1 = val (gated); out0 = feats*val (out)
// ---------------------------------------------------------------------------
__global__ __launch_bounds__(256, 3)
void gemm_mfma(const _Float16* __restrict__ Ah, const _Float16* __restrict__ Al,
               const _Float16* __restrict__ Wh, const _Float16* __restrict__ Wl,
               const float* __restrict__ bias, float alpha,
               _Float16* __restrict__ outb,
               float* __restrict__ out0, float* __restrict__ out1,
               const float* __restrict__ feats, int mode)
{
  __shared__ _Float16 Ash[128][40];
  __shared__ _Float16 Asl[128][40];
  __shared__ _Float16 Wsh[128][40];
  __shared__ _Float16 Wsl[128][40];

  const int tid  = threadIdx.x;
  const int lane = tid & 63, wid = tid >> 6;
  const int l15  = lane & 15, l4 = lane >> 4;
  const int wr   = wid >> 1, wc = wid & 1;     // wave tile 64x64
  const int arow0 = blockIdx.x * 128;
  const int wrow0 = blockIdx.y * 128;

  f32x4 acc[4][4];
#pragma unroll
  for (int m = 0; m < 4; ++m)
#pragma unroll
    for (int n = 0; n < 4; ++n) acc[m][n] = f32x4{0.f, 0.f, 0.f, 0.f};

  for (int k0 = 0; k0 < Dc; k0 += 32) {
    __syncthreads();
#pragma unroll
    for (int p = 0; p < 2; ++p) {
      int e = tid + 256 * p;
      int r = e >> 2, c8 = (e & 3) * 8;
      size_t ao = (size_t)(arow0 + r) * Dc + k0 + c8;
      size_t wo = (size_t)(wrow0 + r) * Dc + k0 + c8;
      uint4 a0 = *reinterpret_cast<const uint4*>(Ah + ao);
      uint4 a1 = *reinterpret_cast<const uint4*>(Al + ao);
      uint4 w0 = *reinterpret_cast<const uint4*>(Wh + wo);
      uint4 w1 = *reinterpret_cast<const uint4*>(Wl + wo);
      *reinterpret_cast<uint4*>(&Ash[r][c8]) = a0;
      *reinterpret_cast<uint4*>(&Asl[r][c8]) = a1;
      *reinterpret_cast<uint4*>(&Wsh[r][c8]) = w0;
      *reinterpret_cast<uint4*>(&Wsl[r][c8]) = w1;
    }
    __syncthreads();

    f16x8 bh[4], bl[4];
#pragma unroll
    for (int n = 0; n < 4; ++n) {
      bh[n] = *reinterpret_cast<const f16x8*>(&Wsh[wc * 64 + n * 16 + l15][l4 * 8]);
      bl[n] = *reinterpret_cast<const f16x8*>(&Wsl[wc * 64 + n * 16 + l15][l4 * 8]);
    }
#pragma unroll
    for (int m = 0; m < 4; ++m) {
      f16x8 ah = *reinterpret_cast<const f16x8*>(&Ash[wr * 64 + m * 16 + l15][l4 * 8]);
      f16x8 al = *reinterpret_cast<const f16x8*>(&Asl[wr * 64 + m * 16 + l15][l4 * 8]);
#pragma unroll
      for (int n = 0; n < 4; ++n) {
        acc[m][n] = __builtin_amdgcn_mfma_f32_16x16x32_f16(ah, bh[n], acc[m][n], 0, 0, 0);
        acc[m][n] = __builtin_amdgcn_mfma_f32_16x16x32_f16(ah, bl[n], acc[m][n], 0, 0, 0);
        acc[m][n] = __builtin_amdgcn_mfma_f32_16x16x32_f16(al, bh[n], acc[m][n], 0, 0, 0);
      }
    }
  }

  // epilogue: C/D layout col = l15, row = l4*4 + reg
#pragma unroll
  for (int m = 0; m < 4; ++m) {
#pragma unroll
    for (int n = 0; n < 4; ++n) {
#pragma unroll
      for (int reg = 0; reg < 4; ++reg) {
        int r = arow0 + wr * 64 + m * 16 + l4 * 4 + reg;
        int c = wrow0 + wc * 64 + n * 16 + l15;
        float bval = (mode == 1) ? bias[r] : bias[c];
        float val = (acc[m][n][reg] + bval) * alpha;
        if (mode == 0) {
          int b = r >> 11, s = r & (Sc - 1), h = c >> 6, hd = c & 63;
          outb[(((size_t)b * Hc + h) * Sc + s) * HDc + hd] = (_Float16)val;
        } else if (mode == 1) {
          int h = r >> 6, hd = r & 63, b = c >> 11, s = c & (Sc - 1);
          outb[(((size_t)b * Hc + h) * HDc + hd) * Sc + s] = (_Float16)val;
        } else {
          out1[(size_t)r * Dc + c] = val;
          out0[(size_t)r * Dc + c] = feats[(size_t)r * Dc + c] * val;
        }
      }
    }
  }
}

// ---------------------------------------------------------------------------
// Flash attention, f16 MFMA. Block = 4 waves; wave owns 16 q-rows (QB=64).
// Swapped QK^T (S^T layout: lane owns one q-row, per-lane scalar max),
// packed b64 P-stores (conflict-free), double-buffered K/V (1 barrier/tile),
// defer-max (THR=8), row-sums via ones-MFMA.
// ---------------------------------------------------------------------------
#define QB 64
#define KB 64
#define NT (Sc / KB)

__global__ __launch_bounds__(256, 2)
void attn_mfma(const _Float16* __restrict__ q,
               const _Float16* __restrict__ k,
               const _Float16* __restrict__ vt,
               const float* __restrict__ mask,
               _Float16* __restrict__ ctxh, _Float16* __restrict__ ctxl)
{
  __shared__ _Float16 Ks[2][KB][72];
  __shared__ _Float16 Vs[2][HDc][72];
  __shared__ _Float16 Ps[4][16][72];

  const int tid  = threadIdx.x;
  const int lane = tid & 63;
  const int wave = tid >> 6;
  const int l15  = lane & 15;
  const int l4   = lane >> 4;

  const int nqb  = Sc / QB;            // 32
  const int head = blockIdx.x / nqb;   // b*H + h
  const int q0   = (blockIdx.x % nqb) * QB;
  const int b    = head / Hc;
  const int h    = head % Hc;

  const _Float16* qbase  = q  + ((size_t)head * Sc + q0 + wave * 16) * HDc;
  const _Float16* kbase  = k  + (size_t)head * Sc * HDc;
  const _Float16* vtbase = vt + (size_t)head * HDc * Sc;
  const float*    mbase  = mask + ((size_t)b * Sc + q0 + wave * 16) * Sc;

  const int sr  = tid >> 3;          // staging row 0..31 (+32)
  const int sc8 = (tid & 7) * 8;     // staging col (f16 units)

  f16x8 qf[2];
#pragma unroll
  for (int f = 0; f < 2; ++f)
    qf[f] = *reinterpret_cast<const f16x8*>(
        qbase + (size_t)l15 * HDc + l4 * 8 + 32 * f);

  f16x8 ones;
#pragma unroll
  for (int i = 0; i < 8; ++i) ones[i] = (_Float16)1.0f;

  f32x4 O[4];
#pragma unroll
  for (int dt = 0; dt < 4; ++dt) O[dt] = f32x4{0.f, 0.f, 0.f, 0.f};
  float m_q = -3e38f;      // running max of q-row l15 (per-lane scalar)
  float l_r[4];            // row sums in O layout (q = l4*4+reg)
#pragma unroll
  for (int r = 0; r < 4; ++r) l_r[r] = 0.f;

  // prologue: stage tile 0 into buffer 0
#pragma unroll
  for (int p = 0; p < 2; ++p) {
    int r = sr + 32 * p;
    *reinterpret_cast<uint4*>(&Ks[0][r][sc8]) =
        *reinterpret_cast<const uint4*>(kbase + (size_t)r * HDc + sc8);
    *reinterpret_cast<uint4*>(&Vs[0][r][sc8]) =
        *reinterpret_cast<const uint4*>(vtbase + (size_t)r * Sc + sc8);
  }

  for (int kt = 0; kt < NT; ++kt) {
    const int k0 = kt * KB;
    const int cur = kt & 1, nxt = cur ^ 1;
    __syncthreads();  // publish buf[cur]; prior reads of buf[nxt] done

    // issue next tile's global loads (consumed at bottom, after PV)
    uint4 kr0, kr1, vr0, vr1;
    const bool pf = (kt + 1) < NT;
    if (pf) {
      const int k1 = k0 + KB;
      kr0 = *reinterpret_cast<const uint4*>(kbase + (size_t)(k1 + sr) * HDc + sc8);
      kr1 = *reinterpret_cast<const uint4*>(kbase + (size_t)(k1 + sr + 32) * HDc + sc8);
      vr0 = *reinterpret_cast<const uint4*>(vtbase + (size_t)sr * Sc + k1 + sc8);
      vr1 = *reinterpret_cast<const uint4*>(vtbase + (size_t)(sr + 32) * Sc + k1 + sc8);
    }

    // S^T = K Q^T : lane holds q = l15, k = 16*nt + l4*4 + reg
    f32x4 s[4];
    __builtin_amdgcn_s_setprio(1);
#pragma unroll
    for (int nt = 0; nt < 4; ++nt) {
      f32x4 acc = f32x4{0.f, 0.f, 0.f, 0.f};
      acc = __builtin_amdgcn_mfma_f32_16x16x32_f16(
          *reinterpret_cast<const f16x8*>(&Ks[cur][16 * nt + l15][l4 * 8]),
          qf[0], acc, 0, 0, 0);
      acc = __builtin_amdgcn_mfma_f32_16x16x32_f16(
          *reinterpret_cast<const f16x8*>(&Ks[cur][16 * nt + l15][l4 * 8 + 32]),
          qf[1], acc, 0, 0, 0);
      s[nt] = acc;
    }
    __builtin_amdgcn_s_setprio(0);

    // + mask: k contiguous per lane -> float4 loads
#pragma unroll
    for (int nt = 0; nt < 4; ++nt) {
      float4 mv = *reinterpret_cast<const float4*>(
          mbase + (size_t)l15 * Sc + k0 + 16 * nt + l4 * 4);
      s[nt][0] += mv.x; s[nt][1] += mv.y; s[nt][2] += mv.z; s[nt][3] += mv.w;
    }

    // defer-max: per-lane scalar max over this lane's 16 scores
    float lm = s[0][0];
#pragma unroll
    for (int nt = 0; nt < 4; ++nt)
#pragma unroll
      for (int reg = 0; reg < 4; ++reg) lm = fmaxf(lm, s[nt][reg]);

    if (!__all(lm - m_q <= 8.0f)) {
      // rare path: reduce across the 4 lanes sharing q=l15 (lane bits 4,5)
      float vm = fmaxf(lm, __shfl_xor(lm, 16));
      vm = fmaxf(vm, __shfl_xor(vm, 32));
      float mn = fmaxf(m_q, vm);
      float cc = __expf(m_q - mn);
      m_q = mn;
      // rescale O/l (O rows are q = l4*4+reg -> fetch cc from lane q)
#pragma unroll
      for (int reg = 0; reg < 4; ++reg) {
        float ccq = __shfl(cc, l4 * 4 + reg);
        l_r[reg] *= ccq;
#pragma unroll
        for (int dt = 0; dt < 4; ++dt) O[dt][reg] *= ccq;
      }
    }

    // P = exp(s - m), packed 8B stores (conflict-free)
#pragma unroll
    for (int nt = 0; nt < 4; ++nt) {
      float p0 = __expf(s[nt][0] - m_q);
      float p1 = __expf(s[nt][1] - m_q);
      float p2 = __expf(s[nt][2] - m_q);
      float p3 = __expf(s[nt][3] - m_q);
      union { uint2 u; fp16v2 h[2]; } pk;
      pk.h[0] = __builtin_amdgcn_cvt_pkrtz(p0, p1);
      pk.h[1] = __builtin_amdgcn_cvt_pkrtz(p2, p3);
      *reinterpret_cast<uint2*>(&Ps[wave][l15][16 * nt + l4 * 4]) = pk.u;
    }

    asm volatile("" ::: "memory");  // order Ps writes before reads (same wave)

    f16x8 pa0 = *reinterpret_cast<const f16x8*>(&Ps[wave][l15][l4 * 8]);
    f16x8 pa1 = *reinterpret_cast<const f16x8*>(&Ps[wave][l15][l4 * 8 + 32]);

    __builtin_amdgcn_s_setprio(1);
    // row sums via ones-MFMA: D[row][*] = sum_k P[row][k]
    f32x4 lacc = f32x4{0.f, 0.f, 0.f, 0.f};
    lacc = __builtin_amdgcn_mfma_f32_16x16x32_f16(pa0, ones, lacc, 0, 0, 0);
    lacc = __builtin_amdgcn_mfma_f32_16x16x32_f16(pa1, ones, lacc, 0, 0, 0);

    // O += P V
#pragma unroll
    for (int dt = 0; dt < 4; ++dt) {
      O[dt] = __builtin_amdgcn_mfma_f32_16x16x32_f16(
          pa0, *reinterpret_cast<const f16x8*>(&Vs[cur][16 * dt + l15][l4 * 8]),
          O[dt], 0, 0, 0);
      O[dt] = __builtin_amdgcn_mfma_f32_16x16x32_f16(
          pa1, *reinterpret_cast<const f16x8*>(&Vs[cur][16 * dt + l15][l4 * 8 + 32]),
          O[dt], 0, 0, 0);
    }
    __builtin_amdgcn_s_setprio(0);

#pragma unroll
    for (int reg = 0; reg < 4; ++reg) l_r[reg] += lacc[reg];

    // land prefetched tile into buf[nxt] (after PV; latency was hidden)
    if (pf) {
      *reinterpret_cast<uint4*>(&Ks[nxt][sr][sc8])      = kr0;
      *reinterpret_cast<uint4*>(&Ks[nxt][sr + 32][sc8]) = kr1;
      *reinterpret_cast<uint4*>(&Vs[nxt][sr][sc8])      = vr0;
      *reinterpret_cast<uint4*>(&Vs[nxt][sr + 32][sc8]) = vr1;
    }
  }

  float inv[4];
#pragma unroll
  for (int reg = 0; reg < 4; ++reg) inv[reg] = 1.0f / l_r[reg];
#pragma unroll
  for (int dt = 0; dt < 4; ++dt)
#pragma unroll
    for (int reg = 0; reg < 4; ++reg) {
      int row = q0 + wave * 16 + l4 * 4 + reg;
      size_t addr = ((size_t)b * Sc + row) * Dc + h * HDc + l15 + 16 * dt;
      float val = O[dt][reg] * inv[reg];
      _Float16 hh = (_Float16)val;
      ctxh[addr] = hh;
      ctxl[addr] = (_Float16)(val - (float)hh);
    }
}

// ---------------------------------------------------------------------------
extern "C" void kernel_launch(void* const* d_in, const int* in_sizes, int n_in,
                              void* d_out, int out_size, void* d_ws, size_t ws_size,
                              hipStream_t stream) {
  const float* feats = (const float*)d_in[0];
  const float* mask  = (const float*)d_in[1];
  const float* wq    = (const float*)d_in[2];
  const float* bq    = (const float*)d_in[3];
  const float* wk    = (const float*)d_in[4];
  const float* bk    = (const float*)d_in[5];
  const float* wv    = (const float*)d_in[6];
  const float* bv    = (const float*)d_in[7];
  const float* wo    = (const float*)d_in[8];
  const float* bo    = (const float*)d_in[9];

  char* ws = (char*)d_ws;
  const size_t MB = (size_t)1 << 20;
  _Float16* fh  = (_Float16*)(ws);             // 8 MB
  _Float16* fl  = (_Float16*)(ws + 8  * MB);   // 8 MB
  _Float16* wqh = (_Float16*)(ws + 16 * MB);
  _Float16* wql = (_Float16*)(ws + 18 * MB);
  _Float16* wkh = (_Float16*)(ws + 20 * MB);
  _Float16* wkl = (_Float16*)(ws + 22 * MB);
  _Float16* wvh = (_Float16*)(ws + 24 * MB);
  _Float16* wvl = (_Float16*)(ws + 26 * MB);
  _Float16* woh = (_Float16*)(ws + 28 * MB);
  _Float16* wol = (_Float16*)(ws + 30 * MB);
  _Float16* qb  = (_Float16*)(ws + 32 * MB);
  _Float16* kb  = (_Float16*)(ws + 40 * MB);
  _Float16* vtb = (_Float16*)(ws + 48 * MB);
  _Float16* ctxh = (_Float16*)(ws + 56 * MB);
  _Float16* ctxl = (_Float16*)(ws + 64 * MB);  // end: 72 MB

  float* out   = (float*)d_out;
  float* gated = out + 4194304;

  // precision splits
  split_kernel<<<4096, 256, 0, stream>>>(feats, fh, fl, 1048576);
  split_kernel<<<1024, 256, 0, stream>>>(wq, wqh, wql, 262144);
  split_kernel<<<1024, 256, 0, stream>>>(wk, wkh, wkl, 262144);
  split_kernel<<<1024, 256, 0, stream>>>(wv, wvh, wvl, 262144);
  split_kernel<<<1024, 256, 0, stream>>>(wo, woh, wol, 262144);

  dim3 gqk(NROWS / 128, Dc / 128);   // (32, 8)
  dim3 gvt(Dc / 128, NROWS / 128);   // (8, 32)
  gemm_mfma<<<gqk, 256, 0, stream>>>(fh, fl, wqh, wql, bq, 0.125f, qb,
                                     nullptr, nullptr, nullptr, 0);
  gemm_mfma<<<gqk, 256, 0, stream>>>(fh, fl, wkh, wkl, bk, 1.0f, kb,
                                     nullptr, nullptr, nullptr, 0);
  // V^T = wv @ feats^T  (rows = o-index, cols = token)
  gemm_mfma<<<gvt, 256, 0, stream>>>(wvh, wvl, fh, fl, bv, 1.0f, vtb,
                                     nullptr, nullptr, nullptr, 1);

  attn_mfma<<<Bc * Hc * (Sc / QB), 256, 0, stream>>>(qb, kb, vtb, mask, ctxh, ctxl);

  gemm_mfma<<<gqk, 256, 0, stream>>>(ctxh, ctxl, woh, wol, bo, 1.0f, nullptr,
                                     out, gated, feats, 2);
}

// Round 9
// 318.357 us; speedup vs baseline: 1.0687x; 1.0687x over previous
//
#include <hip/hip_runtime.h>
#include <math.h>

#define Bc 2
#define Sc 2048
#define Dc 1024
#define Hc 16
#define HDc 64
#define NROWS 4096  // B*S

typedef __attribute__((ext_vector_type(8))) _Float16 f16x8;
typedef __attribute__((ext_vector_type(4))) _Float16 f16x4;
typedef __attribute__((ext_vector_type(2))) __fp16 fp16v2;
typedef __attribute__((ext_vector_type(4))) float f32x4;

// ---------------------------------------------------------------------------
// fp32 -> f16 hi + f16 lo  (x = hi + lo, lo = x - (float)hi)
// ---------------------------------------------------------------------------
__global__ __launch_bounds__(256)
void split_kernel(const float* __restrict__ src, _Float16* __restrict__ hi,
                  _Float16* __restrict__ lo, int n4)
{
  int i = blockIdx.x * 256 + threadIdx.x;
  if (i >= n4) return;
  float4 v = reinterpret_cast<const float4*>(src)[i];
  f16x4 h, l;
  h[0] = (_Float16)v.x; l[0] = (_Float16)(v.x - (float)h[0]);
  h[1] = (_Float16)v.y; l[1] = (_Float16)(v.y - (float)h[1]);
  h[2] = (_Float16)v.z; l[2] = (_Float16)(v.z - (float)h[2]);
  h[3] = (_Float16)v.w; l[3] = (_Float16)(v.w - (float)h[3]);
  reinterpret_cast<f16x4*>(hi)[i] = h;
  reinterpret_cast<f16x4*>(lo)[i] = l;
}

// ---------------------------------------------------------------------------
// Split-precision MFMA GEMM: C = (A@W^T + bias)*alpha via f16 hi/lo (3 MFMA).
//   mode 0: f16 head-split -> outb [B,H,S,HD]            (rows=B*S, cols=D)
//   mode 1: f16, rows are the o-index -> outb [B,H,HD,S] (rows=D, cols=B*S)
//           (bias indexed by ROW)
//   mode 2: fp32: out1 = val (gated); out0 = feats*val (out)
// ---------------------------------------------------------------------------
__global__ __launch_bounds__(256, 3)
void gemm_mfma(const _Float16* __restrict__ Ah, const _Float16* __restrict__ Al,
               const _Float16* __restrict__ Wh, const _Float16* __restrict__ Wl,
               const float* __restrict__ bias, float alpha,
               _Float16* __restrict__ outb,
               float* __restrict__ out0, float* __restrict__ out1,
               const float* __restrict__ feats, int mode)
{
  __shared__ _Float16 Ash[128][40];
  __shared__ _Float16 Asl[128][40];
  __shared__ _Float16 Wsh[128][40];
  __shared__ _Float16 Wsl[128][40];

  const int tid  = threadIdx.x;
  const int lane = tid & 63, wid = tid >> 6;
  const int l15  = lane & 15, l4 = lane >> 4;
  const int wr   = wid >> 1, wc = wid & 1;     // wave tile 64x64
  const int arow0 = blockIdx.x * 128;
  const int wrow0 = blockIdx.y * 128;

  f32x4 acc[4][4];
#pragma unroll
  for (int m = 0; m < 4; ++m)
#pragma unroll
    for (int n = 0; n < 4; ++n) acc[m][n] = f32x4{0.f, 0.f, 0.f, 0.f};

  for (int k0 = 0; k0 < Dc; k0 += 32) {
    __syncthreads();
#pragma unroll
    for (int p = 0; p < 2; ++p) {
      int e = tid + 256 * p;
      int r = e >> 2, c8 = (e & 3) * 8;
      size_t ao = (size_t)(arow0 + r) * Dc + k0 + c8;
      size_t wo = (size_t)(wrow0 + r) * Dc + k0 + c8;
      uint4 a0 = *reinterpret_cast<const uint4*>(Ah + ao);
      uint4 a1 = *reinterpret_cast<const uint4*>(Al + ao);
      uint4 w0 = *reinterpret_cast<const uint4*>(Wh + wo);
      uint4 w1 = *reinterpret_cast<const uint4*>(Wl + wo);
      *reinterpret_cast<uint4*>(&Ash[r][c8]) = a0;
      *reinterpret_cast<uint4*>(&Asl[r][c8]) = a1;
      *reinterpret_cast<uint4*>(&Wsh[r][c8]) = w0;
      *reinterpret_cast<uint4*>(&Wsl[r][c8]) = w1;
    }
    __syncthreads();

    f16x8 bh[4], bl[4];
#pragma unroll
    for (int n = 0; n < 4; ++n) {
      bh[n] = *reinterpret_cast<const f16x8*>(&Wsh[wc * 64 + n * 16 + l15][l4 * 8]);
      bl[n] = *reinterpret_cast<const f16x8*>(&Wsl[wc * 64 + n * 16 + l15][l4 * 8]);
    }
#pragma unroll
    for (int m = 0; m < 4; ++m) {
      f16x8 ah = *reinterpret_cast<const f16x8*>(&Ash[wr * 64 + m * 16 + l15][l4 * 8]);
      f16x8 al = *reinterpret_cast<const f16x8*>(&Asl[wr * 64 + m * 16 + l15][l4 * 8]);
#pragma unroll
      for (int n = 0; n < 4; ++n) {
        acc[m][n] = __builtin_amdgcn_mfma_f32_16x16x32_f16(ah, bh[n], acc[m][n], 0, 0, 0);
        acc[m][n] = __builtin_amdgcn_mfma_f32_16x16x32_f16(ah, bl[n], acc[m][n], 0, 0, 0);
        acc[m][n] = __builtin_amdgcn_mfma_f32_16x16x32_f16(al, bh[n], acc[m][n], 0, 0, 0);
      }
    }
  }

  // epilogue: C/D layout col = l15, row = l4*4 + reg
#pragma unroll
  for (int m = 0; m < 4; ++m) {
#pragma unroll
    for (int n = 0; n < 4; ++n) {
#pragma unroll
      for (int reg = 0; reg < 4; ++reg) {
        int r = arow0 + wr * 64 + m * 16 + l4 * 4 + reg;
        int c = wrow0 + wc * 64 + n * 16 + l15;
        float bval = (mode == 1) ? bias[r] : bias[c];
        float val = (acc[m][n][reg] + bval) * alpha;
        if (mode == 0) {
          int b = r >> 11, s = r & (Sc - 1), h = c >> 6, hd = c & 63;
          outb[(((size_t)b * Hc + h) * Sc + s) * HDc + hd] = (_Float16)val;
        } else if (mode == 1) {
          int h = r >> 6, hd = r & 63, b = c >> 11, s = c & (Sc - 1);
          outb[(((size_t)b * Hc + h) * HDc + hd) * Sc + s] = (_Float16)val;
        } else {
          out1[(size_t)r * Dc + c] = val;
          out0[(size_t)r * Dc + c] = feats[(size_t)r * Dc + c] * val;
        }
      }
    }
  }
}

// ---------------------------------------------------------------------------
// Flash attention, f16 MFMA. Block = 8 waves (QB=128); wave owns 16 q-rows.
// XOR-swizzled linear K/V LDS (conflict-free ds_read_b128), double-buffered
// (1 barrier/tile), swapped QK^T (lane owns one q-row), defer-max (THR=8),
// packed P-stores, row-sums via ones-MFMA.
// ---------------------------------------------------------------------------
#define QB 128
#define KB 64
#define NT (Sc / KB)

__global__ __launch_bounds__(512, 4)
void attn_mfma(const _Float16* __restrict__ q,
               const _Float16* __restrict__ k,
               const _Float16* __restrict__ vt,
               const float* __restrict__ mask,
               _Float16* __restrict__ ctxh, _Float16* __restrict__ ctxl)
{
  __shared__ _Float16 Ks[2][KB * 64];        // linear, XOR-swizzled
  __shared__ _Float16 Vs[2][HDc * 64];       // linear, XOR-swizzled
  __shared__ _Float16 Ps[8][16][72];         // per-wave P tile (+8 pad)

  const int tid  = threadIdx.x;
  const int lane = tid & 63;
  const int wave = tid >> 6;                 // 0..7
  const int l15  = lane & 15;
  const int l4   = lane >> 4;

  const int nqb  = Sc / QB;                  // 16
  const int head = blockIdx.x / nqb;         // b*H + h
  const int q0   = (blockIdx.x % nqb) * QB;
  const int b    = head / Hc;
  const int h    = head % Hc;

  const _Float16* qbase  = q  + ((size_t)head * Sc + q0 + wave * 16) * HDc;
  const _Float16* kbase  = k  + (size_t)head * Sc * HDc;
  const _Float16* vtbase = vt + (size_t)head * HDc * Sc;
  const float*    mbase  = mask + ((size_t)b * Sc + q0 + wave * 16) * Sc;

  // staging: one 16B chunk per thread per buffer (512 thr = 64 rows x 8 cols)
  const int srow  = tid >> 3;                // 0..63
  const int scol  = tid & 7;                 // 16B chunk col
  const int sofs  = srow * 64 + (scol ^ (srow & 7)) * 8;  // swizzled LDS ofs

  // frag-read swizzled column offsets (row&7 == l15&7 for all nt/dt)
  const int c0 = ((l4)     ^ (l15 & 7)) * 8;
  const int c1 = ((l4 + 4) ^ (l15 & 7)) * 8;

  f16x8 qf[2];
#pragma unroll
  for (int f = 0; f < 2; ++f)
    qf[f] = *reinterpret_cast<const f16x8*>(
        qbase + (size_t)l15 * HDc + l4 * 8 + 32 * f);

  f16x8 ones;
#pragma unroll
  for (int i = 0; i < 8; ++i) ones[i] = (_Float16)1.0f;

  f32x4 O[4];
#pragma unroll
  for (int dt = 0; dt < 4; ++dt) O[dt] = f32x4{0.f, 0.f, 0.f, 0.f};
  float m_q = -3e38f;      // running max of q-row l15 (per-lane scalar)
  float l_r[4];            // row sums in O layout (q = l4*4+reg)
#pragma unroll
  for (int r = 0; r < 4; ++r) l_r[r] = 0.f;

  // prologue: stage tile 0 into buffer 0
  *reinterpret_cast<uint4*>(&Ks[0][sofs]) =
      *reinterpret_cast<const uint4*>(kbase + (size_t)srow * HDc + scol * 8);
  *reinterpret_cast<uint4*>(&Vs[0][sofs]) =
      *reinterpret_cast<const uint4*>(vtbase + (size_t)srow * Sc + scol * 8);

  for (int kt = 0; kt < NT; ++kt) {
    const int k0 = kt * KB;
    const int cur = kt & 1, nxt = cur ^ 1;
    __syncthreads();  // buf[cur] published; prior reads of buf[nxt] done

    // issue next tile's global loads (landed after PV)
    uint4 kr, vr;
    const bool pf = (kt + 1) < NT;
    if (pf) {
      const int k1 = k0 + KB;
      kr = *reinterpret_cast<const uint4*>(kbase + (size_t)(k1 + srow) * HDc + scol * 8);
      vr = *reinterpret_cast<const uint4*>(vtbase + (size_t)srow * Sc + k1 + scol * 8);
    }

    // S^T = K Q^T : lane holds q = l15, k = 16*nt + l4*4 + reg
    f32x4 s[4];
    __builtin_amdgcn_s_setprio(1);
#pragma unroll
    for (int nt = 0; nt < 4; ++nt) {
      const int krow = (16 * nt + l15) * 64;
      f32x4 acc = f32x4{0.f, 0.f, 0.f, 0.f};
      acc = __builtin_amdgcn_mfma_f32_16x16x32_f16(
          *reinterpret_cast<const f16x8*>(&Ks[cur][krow + c0]), qf[0], acc, 0, 0, 0);
      acc = __builtin_amdgcn_mfma_f32_16x16x32_f16(
          *reinterpret_cast<const f16x8*>(&Ks[cur][krow + c1]), qf[1], acc, 0, 0, 0);
      s[nt] = acc;
    }
    __builtin_amdgcn_s_setprio(0);

    // + mask: k contiguous per lane -> float4 loads
#pragma unroll
    for (int nt = 0; nt < 4; ++nt) {
      float4 mv = *reinterpret_cast<const float4*>(
          mbase + (size_t)l15 * Sc + k0 + 16 * nt + l4 * 4);
      s[nt][0] += mv.x; s[nt][1] += mv.y; s[nt][2] += mv.z; s[nt][3] += mv.w;
    }

    // defer-max: per-lane scalar max over this lane's 16 scores
    float lm = s[0][0];
#pragma unroll
    for (int nt = 0; nt < 4; ++nt)
#pragma unroll
      for (int reg = 0; reg < 4; ++reg) lm = fmaxf(lm, s[nt][reg]);

    if (!__all(lm - m_q <= 8.0f)) {
      // rare path: reduce across the 4 lanes sharing q=l15 (lane bits 4,5)
      float vm = fmaxf(lm, __shfl_xor(lm, 16));
      vm = fmaxf(vm, __shfl_xor(vm, 32));
      float mn = fmaxf(m_q, vm);
      float cc = __expf(m_q - mn);
      m_q = mn;
#pragma unroll
      for (int reg = 0; reg < 4; ++reg) {
        float ccq = __shfl(cc, l4 * 4 + reg);
        l_r[reg] *= ccq;
#pragma unroll
        for (int dt = 0; dt < 4; ++dt) O[dt][reg] *= ccq;
      }
    }

    // P = exp(s - m), packed 8B stores
#pragma unroll
    for (int nt = 0; nt < 4; ++nt) {
      float p0 = __expf(s[nt][0] - m_q);
      float p1 = __expf(s[nt][1] - m_q);
      float p2 = __expf(s[nt][2] - m_q);
      float p3 = __expf(s[nt][3] - m_q);
      union { uint2 u; fp16v2 h[2]; } pk;
      pk.h[0] = __builtin_amdgcn_cvt_pkrtz(p0, p1);
      pk.h[1] = __builtin_amdgcn_cvt_pkrtz(p2, p3);
      *reinterpret_cast<uint2*>(&Ps[wave][l15][16 * nt + l4 * 4]) = pk.u;
    }

    asm volatile("" ::: "memory");  // order Ps writes before reads (same wave)

    f16x8 pa0 = *reinterpret_cast<const f16x8*>(&Ps[wave][l15][l4 * 8]);
    f16x8 pa1 = *reinterpret_cast<const f16x8*>(&Ps[wave][l15][l4 * 8 + 32]);

    __builtin_amdgcn_s_setprio(1);
    // row sums via ones-MFMA: D[row][*] = sum_k P[row][k]
    f32x4 lacc = f32x4{0.f, 0.f, 0.f, 0.f};
    lacc = __builtin_amdgcn_mfma_f32_16x16x32_f16(pa0, ones, lacc, 0, 0, 0);
    lacc = __builtin_amdgcn_mfma_f32_16x16x32_f16(pa1, ones, lacc, 0, 0, 0);

    // O += P V
#pragma unroll
    for (int dt = 0; dt < 4; ++dt) {
      const int vrow = (16 * dt + l15) * 64;
      O[dt] = __builtin_amdgcn_mfma_f32_16x16x32_f16(
          pa0, *reinterpret_cast<const f16x8*>(&Vs[cur][vrow + c0]), O[dt], 0, 0, 0);
      O[dt] = __builtin_amdgcn_mfma_f32_16x16x32_f16(
          pa1, *reinterpret_cast<const f16x8*>(&Vs[cur][vrow + c1]), O[dt], 0, 0, 0);
    }
    __builtin_amdgcn_s_setprio(0);

#pragma unroll
    for (int reg = 0; reg < 4; ++reg) l_r[reg] += lacc[reg];

    // land prefetched tile into buf[nxt] (after PV; latency was hidden)
    if (pf) {
      *reinterpret_cast<uint4*>(&Ks[nxt][sofs]) = kr;
      *reinterpret_cast<uint4*>(&Vs[nxt][sofs]) = vr;
    }
  }

  float inv[4];
#pragma unroll
  for (int reg = 0; reg < 4; ++reg) inv[reg] = 1.0f / l_r[reg];
#pragma unroll
  for (int dt = 0; dt < 4; ++dt)
#pragma unroll
    for (int reg = 0; reg < 4; ++reg) {
      int row = q0 + wave * 16 + l4 * 4 + reg;
      size_t addr = ((size_t)b * Sc + row) * Dc + h * HDc + l15 + 16 * dt;
      float val = O[dt][reg] * inv[reg];
      _Float16 hh = (_Float16)val;
      ctxh[addr] = hh;
      ctxl[addr] = (_Float16)(val - (float)hh);
    }
}

// ---------------------------------------------------------------------------
extern "C" void kernel_launch(void* const* d_in, const int* in_sizes, int n_in,
                              void* d_out, int out_size, void* d_ws, size_t ws_size,
                              hipStream_t stream) {
  const float* feats = (const float*)d_in[0];
  const float* mask  = (const float*)d_in[1];
  const float* wq    = (const float*)d_in[2];
  const float* bq    = (const float*)d_in[3];
  const float* wk    = (const float*)d_in[4];
  const float* bk    = (const float*)d_in[5];
  const float* wv    = (const float*)d_in[6];
  const float* bv    = (const float*)d_in[7];
  const float* wo    = (const float*)d_in[8];
  const float* bo    = (const float*)d_in[9];

  char* ws = (char*)d_ws;
  const size_t MB = (size_t)1 << 20;
  _Float16* fh  = (_Float16*)(ws);             // 8 MB
  _Float16* fl  = (_Float16*)(ws + 8  * MB);   // 8 MB
  _Float16* wqh = (_Float16*)(ws + 16 * MB);
  _Float16* wql = (_Float16*)(ws + 18 * MB);
  _Float16* wkh = (_Float16*)(ws + 20 * MB);
  _Float16* wkl = (_Float16*)(ws + 22 * MB);
  _Float16* wvh = (_Float16*)(ws + 24 * MB);
  _Float16* wvl = (_Float16*)(ws + 26 * MB);
  _Float16* woh = (_Float16*)(ws + 28 * MB);
  _Float16* wol = (_Float16*)(ws + 30 * MB);
  _Float16* qb  = (_Float16*)(ws + 32 * MB);
  _Float16* kb  = (_Float16*)(ws + 40 * MB);
  _Float16* vtb = (_Float16*)(ws + 48 * MB);
  _Float16* ctxh = (_Float16*)(ws + 56 * MB);
  _Float16* ctxl = (_Float16*)(ws + 64 * MB);  // end: 72 MB

  float* out   = (float*)d_out;
  float* gated = out + 4194304;

  // precision splits
  split_kernel<<<4096, 256, 0, stream>>>(feats, fh, fl, 1048576);
  split_kernel<<<1024, 256, 0, stream>>>(wq, wqh, wql, 262144);
  split_kernel<<<1024, 256, 0, stream>>>(wk, wkh, wkl, 262144);
  split_kernel<<<1024, 256, 0, stream>>>(wv, wvh, wvl, 262144);
  split_kernel<<<1024, 256, 0, stream>>>(wo, woh, wol, 262144);

  dim3 gqk(NROWS / 128, Dc / 128);   // (32, 8)
  dim3 gvt(Dc / 128, NROWS / 128);   // (8, 32)
  gemm_mfma<<<gqk, 256, 0, stream>>>(fh, fl, wqh, wql, bq, 0.125f, qb,
                                     nullptr, nullptr, nullptr, 0);
  gemm_mfma<<<gqk, 256, 0, stream>>>(fh, fl, wkh, wkl, bk, 1.0f, kb,
                                     nullptr, nullptr, nullptr, 0);
  // V^T = wv @ feats^T  (rows = o-index, cols = token)
  gemm_mfma<<<gvt, 256, 0, stream>>>(wvh, wvl, fh, fl, bv, 1.0f, vtb,
                                     nullptr, nullptr, nullptr, 1);

  attn_mfma<<<Bc * Hc * (Sc / QB), 512, 0, stream>>>(qb, kb, vtb, mask, ctxh, ctxl);

  gemm_mfma<<<gqk, 256, 0, stream>>>(ctxh, ctxl, woh, wol, bo, 1.0f, nullptr,
                                     out, gated, feats, 2);
}

// Round 10
// 214.731 us; speedup vs baseline: 1.5844x; 1.4826x over previous
//
#include <hip/hip_runtime.h>
#include <math.h>

#define Bc 2
#define Sc 2048
#define Dc 1024
#define Hc 16
#define HDc 64
#define NROWS 4096  // B*S

typedef __attribute__((ext_vector_type(8))) _Float16 f16x8;
typedef __attribute__((ext_vector_type(4))) _Float16 f16x4;
typedef __attribute__((ext_vector_type(2))) __fp16 fp16v2;
typedef __attribute__((ext_vector_type(4))) float f32x4;

// ---------------------------------------------------------------------------
// Fused 5-way fp32 -> f16 hi/lo split (feats, wq, wk, wv, wo).
// wq/wk/wv land packed into wh3/wl3 = [wq; wk; wv] (3072 x 1024).
// ---------------------------------------------------------------------------
__global__ __launch_bounds__(256)
void split5(const float* __restrict__ f,  const float* __restrict__ wq,
            const float* __restrict__ wk, const float* __restrict__ wv,
            const float* __restrict__ wo_,
            _Float16* __restrict__ fh,  _Float16* __restrict__ fl,
            _Float16* __restrict__ wh3, _Float16* __restrict__ wl3,
            _Float16* __restrict__ woh, _Float16* __restrict__ wol)
{
  int blk = blockIdx.x;
  const float* src; _Float16* hi; _Float16* lo; int base;
  if (blk < 4096)      { src = f;   hi = fh;            lo = fl;            base = blk; }
  else if (blk < 5120) { src = wq;  hi = wh3;           lo = wl3;           base = blk - 4096; }
  else if (blk < 6144) { src = wk;  hi = wh3 + 1048576; lo = wl3 + 1048576; base = blk - 5120; }
  else if (blk < 7168) { src = wv;  hi = wh3 + 2097152; lo = wl3 + 2097152; base = blk - 6144; }
  else                 { src = wo_; hi = woh;           lo = wol;           base = blk - 7168; }
  int i = base * 256 + threadIdx.x;
  float4 v = reinterpret_cast<const float4*>(src)[i];
  f16x4 h, l;
  h[0] = (_Float16)v.x; l[0] = (_Float16)(v.x - (float)h[0]);
  h[1] = (_Float16)v.y; l[1] = (_Float16)(v.y - (float)h[1]);
  h[2] = (_Float16)v.z; l[2] = (_Float16)(v.z - (float)h[2]);
  h[3] = (_Float16)v.w; l[3] = (_Float16)(v.w - (float)h[3]);
  reinterpret_cast<f16x4*>(hi)[i] = h;
  reinterpret_cast<f16x4*>(lo)[i] = l;
}

// ---------------------------------------------------------------------------
// Fused QKV split-precision GEMM (3 MFMA hi/lo). A=[4096,1024], W=[3072,1024].
// grid (32, 24) of 128x128 tiles -> 768 blocks = 3/CU.
// Epilogue by column segment: q (*0.125, [B,H,S,HD]), k ([B,H,S,HD]),
// v (V^T [B,H,HD,S], packed f16x4 stores along s).
// ---------------------------------------------------------------------------
__global__ __launch_bounds__(256, 3)
void gemm_qkv(const _Float16* __restrict__ Ah, const _Float16* __restrict__ Al,
              const _Float16* __restrict__ Wh, const _Float16* __restrict__ Wl,
              const float* __restrict__ bq, const float* __restrict__ bk,
              const float* __restrict__ bv,
              _Float16* __restrict__ qb, _Float16* __restrict__ kb,
              _Float16* __restrict__ vtb)
{
  __shared__ _Float16 Ash[128][40];
  __shared__ _Float16 Asl[128][40];
  __shared__ _Float16 Wsh[128][40];
  __shared__ _Float16 Wsl[128][40];

  const int tid  = threadIdx.x;
  const int lane = tid & 63, wid = tid >> 6;
  const int l15  = lane & 15, l4 = lane >> 4;
  const int wr   = wid >> 1, wc = wid & 1;     // wave tile 64x64
  const int arow0 = blockIdx.x * 128;
  const int wrow0 = blockIdx.y * 128;

  f32x4 acc[4][4];
#pragma unroll
  for (int m = 0; m < 4; ++m)
#pragma unroll
    for (int n = 0; n < 4; ++n) acc[m][n] = f32x4{0.f, 0.f, 0.f, 0.f};

  for (int k0 = 0; k0 < Dc; k0 += 32) {
    __syncthreads();
#pragma unroll
    for (int p = 0; p < 2; ++p) {
      int e = tid + 256 * p;
      int r = e >> 2, c8 = (e & 3) * 8;
      size_t ao = (size_t)(arow0 + r) * Dc + k0 + c8;
      size_t wo = (size_t)(wrow0 + r) * Dc + k0 + c8;
      *reinterpret_cast<uint4*>(&Ash[r][c8]) = *reinterpret_cast<const uint4*>(Ah + ao);
      *reinterpret_cast<uint4*>(&Asl[r][c8]) = *reinterpret_cast<const uint4*>(Al + ao);
      *reinterpret_cast<uint4*>(&Wsh[r][c8]) = *reinterpret_cast<const uint4*>(Wh + wo);
      *reinterpret_cast<uint4*>(&Wsl[r][c8]) = *reinterpret_cast<const uint4*>(Wl + wo);
    }
    __syncthreads();

    f16x8 bh[4], bl[4];
#pragma unroll
    for (int n = 0; n < 4; ++n) {
      bh[n] = *reinterpret_cast<const f16x8*>(&Wsh[wc * 64 + n * 16 + l15][l4 * 8]);
      bl[n] = *reinterpret_cast<const f16x8*>(&Wsl[wc * 64 + n * 16 + l15][l4 * 8]);
    }
#pragma unroll
    for (int m = 0; m < 4; ++m) {
      f16x8 ah = *reinterpret_cast<const f16x8*>(&Ash[wr * 64 + m * 16 + l15][l4 * 8]);
      f16x8 al = *reinterpret_cast<const f16x8*>(&Asl[wr * 64 + m * 16 + l15][l4 * 8]);
#pragma unroll
      for (int n = 0; n < 4; ++n) {
        acc[m][n] = __builtin_amdgcn_mfma_f32_16x16x32_f16(ah, bh[n], acc[m][n], 0, 0, 0);
        acc[m][n] = __builtin_amdgcn_mfma_f32_16x16x32_f16(ah, bl[n], acc[m][n], 0, 0, 0);
        acc[m][n] = __builtin_amdgcn_mfma_f32_16x16x32_f16(al, bh[n], acc[m][n], 0, 0, 0);
      }
    }
  }

  // epilogue
#pragma unroll
  for (int m = 0; m < 4; ++m) {
#pragma unroll
    for (int n = 0; n < 4; ++n) {
      int cbase = wrow0 + wc * 64 + n * 16;      // 16-aligned, never crosses 1024
      int seg = cbase >> 10;                     // 0=q, 1=k, 2=v
      int o = (cbase & 1023) + l15;
      int h = o >> 6, hd = o & 63;
      const float* bias = (seg == 0) ? bq : ((seg == 1) ? bk : bv);
      float bval = bias[o];
      float alpha = (seg == 0) ? 0.125f : 1.0f;
      int r0 = arow0 + wr * 64 + m * 16 + l4 * 4;
      int b = r0 >> 11, s0 = r0 & (Sc - 1);
      if (seg == 2) {
        f16x4 pk;
#pragma unroll
        for (int reg = 0; reg < 4; ++reg)
          pk[reg] = (_Float16)((acc[m][n][reg] + bval) * alpha);
        *reinterpret_cast<f16x4*>(
            &vtb[(((size_t)b * Hc + h) * HDc + hd) * Sc + s0]) = pk;
      } else {
        _Float16* dst = (seg == 0) ? qb : kb;
#pragma unroll
        for (int reg = 0; reg < 4; ++reg) {
          float val = (acc[m][n][reg] + bval) * alpha;
          dst[(((size_t)b * Hc + h) * Sc + (s0 + reg)) * HDc + hd] = (_Float16)val;
        }
      }
    }
  }
}

// ---------------------------------------------------------------------------
// Output GEMM (mode-2): 64x128 blocks -> grid (64,8) = 512 blocks = 2/CU.
// out1 = (ctx@wo^T + bo) (gated); out0 = feats * out1 (out).
// ---------------------------------------------------------------------------
__global__ __launch_bounds__(256, 2)
void gemm_wo(const _Float16* __restrict__ Ah, const _Float16* __restrict__ Al,
             const _Float16* __restrict__ Wh, const _Float16* __restrict__ Wl,
             const float* __restrict__ bias,
             float* __restrict__ out0, float* __restrict__ out1,
             const float* __restrict__ feats)
{
  __shared__ _Float16 Ash[64][40];
  __shared__ _Float16 Asl[64][40];
  __shared__ _Float16 Wsh[128][40];
  __shared__ _Float16 Wsl[128][40];

  const int tid  = threadIdx.x;
  const int lane = tid & 63, wid = tid >> 6;
  const int l15  = lane & 15, l4 = lane >> 4;
  const int wr   = wid >> 1, wc = wid & 1;     // wave tile 32x64
  const int arow0 = blockIdx.x * 64;
  const int wrow0 = blockIdx.y * 128;

  f32x4 acc[2][4];
#pragma unroll
  for (int m = 0; m < 2; ++m)
#pragma unroll
    for (int n = 0; n < 4; ++n) acc[m][n] = f32x4{0.f, 0.f, 0.f, 0.f};

  for (int k0 = 0; k0 < Dc; k0 += 32) {
    __syncthreads();
    {
      int r = tid >> 2, c8 = (tid & 3) * 8;
      size_t ao = (size_t)(arow0 + r) * Dc + k0 + c8;
      *reinterpret_cast<uint4*>(&Ash[r][c8]) = *reinterpret_cast<const uint4*>(Ah + ao);
      *reinterpret_cast<uint4*>(&Asl[r][c8]) = *reinterpret_cast<const uint4*>(Al + ao);
    }
#pragma unroll
    for (int p = 0; p < 2; ++p) {
      int e = tid + 256 * p;
      int r = e >> 2, c8 = (e & 3) * 8;
      size_t wo = (size_t)(wrow0 + r) * Dc + k0 + c8;
      *reinterpret_cast<uint4*>(&Wsh[r][c8]) = *reinterpret_cast<const uint4*>(Wh + wo);
      *reinterpret_cast<uint4*>(&Wsl[r][c8]) = *reinterpret_cast<const uint4*>(Wl + wo);
    }
    __syncthreads();

    f16x8 bh[4], bl[4];
#pragma unroll
    for (int n = 0; n < 4; ++n) {
      bh[n] = *reinterpret_cast<const f16x8*>(&Wsh[wc * 64 + n * 16 + l15][l4 * 8]);
      bl[n] = *reinterpret_cast<const f16x8*>(&Wsl[wc * 64 + n * 16 + l15][l4 * 8]);
    }
#pragma unroll
    for (int m = 0; m < 2; ++m) {
      f16x8 ah = *reinterpret_cast<const f16x8*>(&Ash[wr * 32 + m * 16 + l15][l4 * 8]);
      f16x8 al = *reinterpret_cast<const f16x8*>(&Asl[wr * 32 + m * 16 + l15][l4 * 8]);
#pragma unroll
      for (int n = 0; n < 4; ++n) {
        acc[m][n] = __builtin_amdgcn_mfma_f32_16x16x32_f16(ah, bh[n], acc[m][n], 0, 0, 0);
        acc[m][n] = __builtin_amdgcn_mfma_f32_16x16x32_f16(ah, bl[n], acc[m][n], 0, 0, 0);
        acc[m][n] = __builtin_amdgcn_mfma_f32_16x16x32_f16(al, bh[n], acc[m][n], 0, 0, 0);
      }
    }
  }

#pragma unroll
  for (int m = 0; m < 2; ++m) {
#pragma unroll
    for (int n = 0; n < 4; ++n) {
      int c = wrow0 + wc * 64 + n * 16 + l15;
      float bval = bias[c];
#pragma unroll
      for (int reg = 0; reg < 4; ++reg) {
        int r = arow0 + wr * 32 + m * 16 + l4 * 4 + reg;
        float val = acc[m][n][reg] + bval;
        out1[(size_t)r * Dc + c] = val;
        out0[(size_t)r * Dc + c] = feats[(size_t)r * Dc + c] * val;
      }
    }
  }
}

// ---------------------------------------------------------------------------
// Flash attention, f16 MFMA (unchanged from round 9).
// ---------------------------------------------------------------------------
#define QB 128
#define KB 64
#define NT (Sc / KB)

__global__ __launch_bounds__(512, 4)
void attn_mfma(const _Float16* __restrict__ q,
               const _Float16* __restrict__ k,
               const _Float16* __restrict__ vt,
               const float* __restrict__ mask,
               _Float16* __restrict__ ctxh, _Float16* __restrict__ ctxl)
{
  __shared__ _Float16 Ks[2][KB * 64];        // linear, XOR-swizzled
  __shared__ _Float16 Vs[2][HDc * 64];       // linear, XOR-swizzled
  __shared__ _Float16 Ps[8][16][72];         // per-wave P tile (+8 pad)

  const int tid  = threadIdx.x;
  const int lane = tid & 63;
  const int wave = tid >> 6;                 // 0..7
  const int l15  = lane & 15;
  const int l4   = lane >> 4;

  const int nqb  = Sc / QB;                  // 16
  const int head = blockIdx.x / nqb;         // b*H + h
  const int q0   = (blockIdx.x % nqb) * QB;
  const int b    = head / Hc;
  const int h    = head % Hc;

  const _Float16* qbase  = q  + ((size_t)head * Sc + q0 + wave * 16) * HDc;
  const _Float16* kbase  = k  + (size_t)head * Sc * HDc;
  const _Float16* vtbase = vt + (size_t)head * HDc * Sc;
  const float*    mbase  = mask + ((size_t)b * Sc + q0 + wave * 16) * Sc;

  const int srow  = tid >> 3;                // 0..63
  const int scol  = tid & 7;                 // 16B chunk col
  const int sofs  = srow * 64 + (scol ^ (srow & 7)) * 8;

  const int c0 = ((l4)     ^ (l15 & 7)) * 8;
  const int c1 = ((l4 + 4) ^ (l15 & 7)) * 8;

  f16x8 qf[2];
#pragma unroll
  for (int f = 0; f < 2; ++f)
    qf[f] = *reinterpret_cast<const f16x8*>(
        qbase + (size_t)l15 * HDc + l4 * 8 + 32 * f);

  f16x8 ones;
#pragma unroll
  for (int i = 0; i < 8; ++i) ones[i] = (_Float16)1.0f;

  f32x4 O[4];
#pragma unroll
  for (int dt = 0; dt < 4; ++dt) O[dt] = f32x4{0.f, 0.f, 0.f, 0.f};
  float m_q = -3e38f;
  float l_r[4];
#pragma unroll
  for (int r = 0; r < 4; ++r) l_r[r] = 0.f;

  *reinterpret_cast<uint4*>(&Ks[0][sofs]) =
      *reinterpret_cast<const uint4*>(kbase + (size_t)srow * HDc + scol * 8);
  *reinterpret_cast<uint4*>(&Vs[0][sofs]) =
      *reinterpret_cast<const uint4*>(vtbase + (size_t)srow * Sc + scol * 8);

  for (int kt = 0; kt < NT; ++kt) {
    const int k0 = kt * KB;
    const int cur = kt & 1, nxt = cur ^ 1;
    __syncthreads();

    uint4 kr, vr;
    const bool pf = (kt + 1) < NT;
    if (pf) {
      const int k1 = k0 + KB;
      kr = *reinterpret_cast<const uint4*>(kbase + (size_t)(k1 + srow) * HDc + scol * 8);
      vr = *reinterpret_cast<const uint4*>(vtbase + (size_t)srow * Sc + k1 + scol * 8);
    }

    f32x4 s[4];
    __builtin_amdgcn_s_setprio(1);
#pragma unroll
    for (int nt = 0; nt < 4; ++nt) {
      const int krow = (16 * nt + l15) * 64;
      f32x4 acc = f32x4{0.f, 0.f, 0.f, 0.f};
      acc = __builtin_amdgcn_mfma_f32_16x16x32_f16(
          *reinterpret_cast<const f16x8*>(&Ks[cur][krow + c0]), qf[0], acc, 0, 0, 0);
      acc = __builtin_amdgcn_mfma_f32_16x16x32_f16(
          *reinterpret_cast<const f16x8*>(&Ks[cur][krow + c1]), qf[1], acc, 0, 0, 0);
      s[nt] = acc;
    }
    __builtin_amdgcn_s_setprio(0);

#pragma unroll
    for (int nt = 0; nt < 4; ++nt) {
      float4 mv = *reinterpret_cast<const float4*>(
          mbase + (size_t)l15 * Sc + k0 + 16 * nt + l4 * 4);
      s[nt][0] += mv.x; s[nt][1] += mv.y; s[nt][2] += mv.z; s[nt][3] += mv.w;
    }

    float lm = s[0][0];
#pragma unroll
    for (int nt = 0; nt < 4; ++nt)
#pragma unroll
      for (int reg = 0; reg < 4; ++reg) lm = fmaxf(lm, s[nt][reg]);

    if (!__all(lm - m_q <= 8.0f)) {
      float vm = fmaxf(lm, __shfl_xor(lm, 16));
      vm = fmaxf(vm, __shfl_xor(vm, 32));
      float mn = fmaxf(m_q, vm);
      float cc = __expf(m_q - mn);
      m_q = mn;
#pragma unroll
      for (int reg = 0; reg < 4; ++reg) {
        float ccq = __shfl(cc, l4 * 4 + reg);
        l_r[reg] *= ccq;
#pragma unroll
        for (int dt = 0; dt < 4; ++dt) O[dt][reg] *= ccq;
      }
    }

#pragma unroll
    for (int nt = 0; nt < 4; ++nt) {
      float p0 = __expf(s[nt][0] - m_q);
      float p1 = __expf(s[nt][1] - m_q);
      float p2 = __expf(s[nt][2] - m_q);
      float p3 = __expf(s[nt][3] - m_q);
      union { uint2 u; fp16v2 h[2]; } pk;
      pk.h[0] = __builtin_amdgcn_cvt_pkrtz(p0, p1);
      pk.h[1] = __builtin_amdgcn_cvt_pkrtz(p2, p3);
      *reinterpret_cast<uint2*>(&Ps[wave][l15][16 * nt + l4 * 4]) = pk.u;
    }

    asm volatile("" ::: "memory");

    f16x8 pa0 = *reinterpret_cast<const f16x8*>(&Ps[wave][l15][l4 * 8]);
    f16x8 pa1 = *reinterpret_cast<const f16x8*>(&Ps[wave][l15][l4 * 8 + 32]);

    __builtin_amdgcn_s_setprio(1);
    f32x4 lacc = f32x4{0.f, 0.f, 0.f, 0.f};
    lacc = __builtin_amdgcn_mfma_f32_16x16x32_f16(pa0, ones, lacc, 0, 0, 0);
    lacc = __builtin_amdgcn_mfma_f32_16x16x32_f16(pa1, ones, lacc, 0, 0, 0);

#pragma unroll
    for (int dt = 0; dt < 4; ++dt) {
      const int vrow = (16 * dt + l15) * 64;
      O[dt] = __builtin_amdgcn_mfma_f32_16x16x32_f16(
          pa0, *reinterpret_cast<const f16x8*>(&Vs[cur][vrow + c0]), O[dt], 0, 0, 0);
      O[dt] = __builtin_amdgcn_mfma_f32_16x16x32_f16(
          pa1, *reinterpret_cast<const f16x8*>(&Vs[cur][vrow + c1]), O[dt], 0, 0, 0);
    }
    __builtin_amdgcn_s_setprio(0);

#pragma unroll
    for (int reg = 0; reg < 4; ++reg) l_r[reg] += lacc[reg];

    if (pf) {
      *reinterpret_cast<uint4*>(&Ks[nxt][sofs]) = kr;
      *reinterpret_cast<uint4*>(&Vs[nxt][sofs]) = vr;
    }
  }

  float inv[4];
#pragma unroll
  for (int reg = 0; reg < 4; ++reg) inv[reg] = 1.0f / l_r[reg];
#pragma unroll
  for (int dt = 0; dt < 4; ++dt)
#pragma unroll
    for (int reg = 0; reg < 4; ++reg) {
      int row = q0 + wave * 16 + l4 * 4 + reg;
      size_t addr = ((size_t)b * Sc + row) * Dc + h * HDc + l15 + 16 * dt;
      float val = O[dt][reg] * inv[reg];
      _Float16 hh = (_Float16)val;
      ctxh[addr] = hh;
      ctxl[addr] = (_Float16)(val - (float)hh);
    }
}

// ---------------------------------------------------------------------------
extern "C" void kernel_launch(void* const* d_in, const int* in_sizes, int n_in,
                              void* d_out, int out_size, void* d_ws, size_t ws_size,
                              hipStream_t stream) {
  const float* feats = (const float*)d_in[0];
  const float* mask  = (const float*)d_in[1];
  const float* wq    = (const float*)d_in[2];
  const float* bq    = (const float*)d_in[3];
  const float* wk    = (const float*)d_in[4];
  const float* bk    = (const float*)d_in[5];
  const float* wv    = (const float*)d_in[6];
  const float* bv    = (const float*)d_in[7];
  const float* wo    = (const float*)d_in[8];
  const float* bo    = (const float*)d_in[9];

  char* ws = (char*)d_ws;
  const size_t MB = (size_t)1 << 20;
  _Float16* fh   = (_Float16*)(ws);             // 8 MB
  _Float16* fl   = (_Float16*)(ws + 8  * MB);   // 8 MB
  _Float16* wh3  = (_Float16*)(ws + 16 * MB);   // 6 MB  [wq;wk;wv] hi
  _Float16* wl3  = (_Float16*)(ws + 22 * MB);   // 6 MB  [wq;wk;wv] lo
  _Float16* woh  = (_Float16*)(ws + 28 * MB);   // 2 MB
  _Float16* wol  = (_Float16*)(ws + 30 * MB);   // 2 MB
  _Float16* qb   = (_Float16*)(ws + 32 * MB);   // 8 MB
  _Float16* kb   = (_Float16*)(ws + 40 * MB);   // 8 MB
  _Float16* vtb  = (_Float16*)(ws + 48 * MB);   // 8 MB
  _Float16* ctxh = (_Float16*)(ws + 56 * MB);   // 8 MB
  _Float16* ctxl = (_Float16*)(ws + 64 * MB);   // 8 MB -> 72 MB total

  float* out   = (float*)d_out;
  float* gated = out + 4194304;

  split5<<<8192, 256, 0, stream>>>(feats, wq, wk, wv, wo,
                                   fh, fl, wh3, wl3, woh, wol);

  gemm_qkv<<<dim3(NROWS / 128, 3072 / 128), 256, 0, stream>>>(
      fh, fl, wh3, wl3, bq, bk, bv, qb, kb, vtb);

  attn_mfma<<<Bc * Hc * (Sc / QB), 512, 0, stream>>>(qb, kb, vtb, mask, ctxh, ctxl);

  gemm_wo<<<dim3(NROWS / 64, Dc / 128), 256, 0, stream>>>(
      ctxh, ctxl, woh, wol, bo, out, gated, feats);
}

// Round 11
// 208.834 us; speedup vs baseline: 1.6291x; 1.0282x over previous
//
#include <hip/hip_runtime.h>
#include <math.h>

#define Bc 2
#define Sc 2048
#define Dc 1024
#define Hc 16
#define HDc 64
#define NROWS 4096  // B*S

typedef __attribute__((ext_vector_type(8))) _Float16 f16x8;
typedef __attribute__((ext_vector_type(4))) _Float16 f16x4;
typedef __attribute__((ext_vector_type(2))) __fp16 fp16v2;
typedef __attribute__((ext_vector_type(4))) float f32x4;

// ---------------------------------------------------------------------------
// Fused 5-way fp32 -> f16 hi/lo split (feats, wq, wk, wv, wo).
// wq/wk/wv land packed into wh3/wl3 = [wq; wk; wv] (3072 x 1024).
// ---------------------------------------------------------------------------
__global__ __launch_bounds__(256)
void split5(const float* __restrict__ f,  const float* __restrict__ wq,
            const float* __restrict__ wk, const float* __restrict__ wv,
            const float* __restrict__ wo_,
            _Float16* __restrict__ fh,  _Float16* __restrict__ fl,
            _Float16* __restrict__ wh3, _Float16* __restrict__ wl3,
            _Float16* __restrict__ woh, _Float16* __restrict__ wol)
{
  int blk = blockIdx.x;
  const float* src; _Float16* hi; _Float16* lo; int base;
  if (blk < 4096)      { src = f;   hi = fh;            lo = fl;            base = blk; }
  else if (blk < 5120) { src = wq;  hi = wh3;           lo = wl3;           base = blk - 4096; }
  else if (blk < 6144) { src = wk;  hi = wh3 + 1048576; lo = wl3 + 1048576; base = blk - 5120; }
  else if (blk < 7168) { src = wv;  hi = wh3 + 2097152; lo = wl3 + 2097152; base = blk - 6144; }
  else                 { src = wo_; hi = woh;           lo = wol;           base = blk - 7168; }
  int i = base * 256 + threadIdx.x;
  float4 v = reinterpret_cast<const float4*>(src)[i];
  f16x4 h, l;
  h[0] = (_Float16)v.x; l[0] = (_Float16)(v.x - (float)h[0]);
  h[1] = (_Float16)v.y; l[1] = (_Float16)(v.y - (float)h[1]);
  h[2] = (_Float16)v.z; l[2] = (_Float16)(v.z - (float)h[2]);
  h[3] = (_Float16)v.w; l[3] = (_Float16)(v.w - (float)h[3]);
  reinterpret_cast<f16x4*>(hi)[i] = h;
  reinterpret_cast<f16x4*>(lo)[i] = l;
}

// ---------------------------------------------------------------------------
// Fused QKV split-precision GEMM (3 MFMA hi/lo). A=[4096,1024], W=[3072,1024].
// grid (32, 24) of 128x128 tiles -> 768 blocks = 3/CU.
// ---------------------------------------------------------------------------
__global__ __launch_bounds__(256, 3)
void gemm_qkv(const _Float16* __restrict__ Ah, const _Float16* __restrict__ Al,
              const _Float16* __restrict__ Wh, const _Float16* __restrict__ Wl,
              const float* __restrict__ bq, const float* __restrict__ bk,
              const float* __restrict__ bv,
              _Float16* __restrict__ qb, _Float16* __restrict__ kb,
              _Float16* __restrict__ vtb)
{
  __shared__ _Float16 Ash[128][40];
  __shared__ _Float16 Asl[128][40];
  __shared__ _Float16 Wsh[128][40];
  __shared__ _Float16 Wsl[128][40];

  const int tid  = threadIdx.x;
  const int lane = tid & 63, wid = tid >> 6;
  const int l15  = lane & 15, l4 = lane >> 4;
  const int wr   = wid >> 1, wc = wid & 1;     // wave tile 64x64
  const int arow0 = blockIdx.x * 128;
  const int wrow0 = blockIdx.y * 128;

  f32x4 acc[4][4];
#pragma unroll
  for (int m = 0; m < 4; ++m)
#pragma unroll
    for (int n = 0; n < 4; ++n) acc[m][n] = f32x4{0.f, 0.f, 0.f, 0.f};

  for (int k0 = 0; k0 < Dc; k0 += 32) {
    __syncthreads();
#pragma unroll
    for (int p = 0; p < 2; ++p) {
      int e = tid + 256 * p;
      int r = e >> 2, c8 = (e & 3) * 8;
      size_t ao = (size_t)(arow0 + r) * Dc + k0 + c8;
      size_t wo = (size_t)(wrow0 + r) * Dc + k0 + c8;
      *reinterpret_cast<uint4*>(&Ash[r][c8]) = *reinterpret_cast<const uint4*>(Ah + ao);
      *reinterpret_cast<uint4*>(&Asl[r][c8]) = *reinterpret_cast<const uint4*>(Al + ao);
      *reinterpret_cast<uint4*>(&Wsh[r][c8]) = *reinterpret_cast<const uint4*>(Wh + wo);
      *reinterpret_cast<uint4*>(&Wsl[r][c8]) = *reinterpret_cast<const uint4*>(Wl + wo);
    }
    __syncthreads();

    f16x8 bh[4], bl[4];
#pragma unroll
    for (int n = 0; n < 4; ++n) {
      bh[n] = *reinterpret_cast<const f16x8*>(&Wsh[wc * 64 + n * 16 + l15][l4 * 8]);
      bl[n] = *reinterpret_cast<const f16x8*>(&Wsl[wc * 64 + n * 16 + l15][l4 * 8]);
    }
#pragma unroll
    for (int m = 0; m < 4; ++m) {
      f16x8 ah = *reinterpret_cast<const f16x8*>(&Ash[wr * 64 + m * 16 + l15][l4 * 8]);
      f16x8 al = *reinterpret_cast<const f16x8*>(&Asl[wr * 64 + m * 16 + l15][l4 * 8]);
#pragma unroll
      for (int n = 0; n < 4; ++n) {
        acc[m][n] = __builtin_amdgcn_mfma_f32_16x16x32_f16(ah, bh[n], acc[m][n], 0, 0, 0);
        acc[m][n] = __builtin_amdgcn_mfma_f32_16x16x32_f16(ah, bl[n], acc[m][n], 0, 0, 0);
        acc[m][n] = __builtin_amdgcn_mfma_f32_16x16x32_f16(al, bh[n], acc[m][n], 0, 0, 0);
      }
    }
  }

  // epilogue
#pragma unroll
  for (int m = 0; m < 4; ++m) {
#pragma unroll
    for (int n = 0; n < 4; ++n) {
      int cbase = wrow0 + wc * 64 + n * 16;      // 16-aligned, never crosses 1024
      int seg = cbase >> 10;                     // 0=q, 1=k, 2=v
      int o = (cbase & 1023) + l15;
      int h = o >> 6, hd = o & 63;
      const float* bias = (seg == 0) ? bq : ((seg == 1) ? bk : bv);
      float bval = bias[o];
      float alpha = (seg == 0) ? 0.125f : 1.0f;
      int r0 = arow0 + wr * 64 + m * 16 + l4 * 4;
      int b = r0 >> 11, s0 = r0 & (Sc - 1);
      if (seg == 2) {
        f16x4 pk;
#pragma unroll
        for (int reg = 0; reg < 4; ++reg)
          pk[reg] = (_Float16)((acc[m][n][reg] + bval) * alpha);
        *reinterpret_cast<f16x4*>(
            &vtb[(((size_t)b * Hc + h) * HDc + hd) * Sc + s0]) = pk;
      } else {
        _Float16* dst = (seg == 0) ? qb : kb;
#pragma unroll
        for (int reg = 0; reg < 4; ++reg) {
          float val = (acc[m][n][reg] + bval) * alpha;
          dst[(((size_t)b * Hc + h) * Sc + (s0 + reg)) * HDc + hd] = (_Float16)val;
        }
      }
    }
  }
}

// ---------------------------------------------------------------------------
// Output GEMM: 64x128 blocks -> grid (64,8) = 512 blocks = 2/CU.
// out1 = (ctx@wo^T + bo) (gated); out0 = feats * out1 (out).
// ---------------------------------------------------------------------------
__global__ __launch_bounds__(256, 2)
void gemm_wo(const _Float16* __restrict__ Ah, const _Float16* __restrict__ Al,
             const _Float16* __restrict__ Wh, const _Float16* __restrict__ Wl,
             const float* __restrict__ bias,
             float* __restrict__ out0, float* __restrict__ out1,
             const float* __restrict__ feats)
{
  __shared__ _Float16 Ash[64][40];
  __shared__ _Float16 Asl[64][40];
  __shared__ _Float16 Wsh[128][40];
  __shared__ _Float16 Wsl[128][40];

  const int tid  = threadIdx.x;
  const int lane = tid & 63, wid = tid >> 6;
  const int l15  = lane & 15, l4 = lane >> 4;
  const int wr   = wid >> 1, wc = wid & 1;     // wave tile 32x64
  const int arow0 = blockIdx.x * 64;
  const int wrow0 = blockIdx.y * 128;

  f32x4 acc[2][4];
#pragma unroll
  for (int m = 0; m < 2; ++m)
#pragma unroll
    for (int n = 0; n < 4; ++n) acc[m][n] = f32x4{0.f, 0.f, 0.f, 0.f};

  for (int k0 = 0; k0 < Dc; k0 += 32) {
    __syncthreads();
    {
      int r = tid >> 2, c8 = (tid & 3) * 8;
      size_t ao = (size_t)(arow0 + r) * Dc + k0 + c8;
      *reinterpret_cast<uint4*>(&Ash[r][c8]) = *reinterpret_cast<const uint4*>(Ah + ao);
      *reinterpret_cast<uint4*>(&Asl[r][c8]) = *reinterpret_cast<const uint4*>(Al + ao);
    }
#pragma unroll
    for (int p = 0; p < 2; ++p) {
      int e = tid + 256 * p;
      int r = e >> 2, c8 = (e & 3) * 8;
      size_t wo = (size_t)(wrow0 + r) * Dc + k0 + c8;
      *reinterpret_cast<uint4*>(&Wsh[r][c8]) = *reinterpret_cast<const uint4*>(Wh + wo);
      *reinterpret_cast<uint4*>(&Wsl[r][c8]) = *reinterpret_cast<const uint4*>(Wl + wo);
    }
    __syncthreads();

    f16x8 bh[4], bl[4];
#pragma unroll
    for (int n = 0; n < 4; ++n) {
      bh[n] = *reinterpret_cast<const f16x8*>(&Wsh[wc * 64 + n * 16 + l15][l4 * 8]);
      bl[n] = *reinterpret_cast<const f16x8*>(&Wsl[wc * 64 + n * 16 + l15][l4 * 8]);
    }
#pragma unroll
    for (int m = 0; m < 2; ++m) {
      f16x8 ah = *reinterpret_cast<const f16x8*>(&Ash[wr * 32 + m * 16 + l15][l4 * 8]);
      f16x8 al = *reinterpret_cast<const f16x8*>(&Asl[wr * 32 + m * 16 + l15][l4 * 8]);
#pragma unroll
      for (int n = 0; n < 4; ++n) {
        acc[m][n] = __builtin_amdgcn_mfma_f32_16x16x32_f16(ah, bh[n], acc[m][n], 0, 0, 0);
        acc[m][n] = __builtin_amdgcn_mfma_f32_16x16x32_f16(ah, bl[n], acc[m][n], 0, 0, 0);
        acc[m][n] = __builtin_amdgcn_mfma_f32_16x16x32_f16(al, bh[n], acc[m][n], 0, 0, 0);
      }
    }
  }

#pragma unroll
  for (int m = 0; m < 2; ++m) {
#pragma unroll
    for (int n = 0; n < 4; ++n) {
      int c = wrow0 + wc * 64 + n * 16 + l15;
      float bval = bias[c];
#pragma unroll
      for (int reg = 0; reg < 4; ++reg) {
        int r = arow0 + wr * 32 + m * 16 + l4 * 4 + reg;
        float val = acc[m][n][reg] + bval;
        out1[(size_t)r * Dc + c] = val;
        out0[(size_t)r * Dc + c] = feats[(size_t)r * Dc + c] * val;
      }
    }
  }
}

// ---------------------------------------------------------------------------
// Flash attention, f16 MFMA. Block = 8 waves (QB=128); wave owns 16 q-rows.
// XOR-swizzled K/V LDS, double-buffered, swapped QK^T, defer-max,
// packed P-stores, ones-MFMA row sums, + mask register-prefetch (t+1).
// ---------------------------------------------------------------------------
#define QB 128
#define KB 64
#define NT (Sc / KB)

__global__ __launch_bounds__(512, 4)
void attn_mfma(const _Float16* __restrict__ q,
               const _Float16* __restrict__ k,
               const _Float16* __restrict__ vt,
               const float* __restrict__ mask,
               _Float16* __restrict__ ctxh, _Float16* __restrict__ ctxl)
{
  __shared__ _Float16 Ks[2][KB * 64];        // linear, XOR-swizzled
  __shared__ _Float16 Vs[2][HDc * 64];       // linear, XOR-swizzled
  __shared__ _Float16 Ps[8][16][72];         // per-wave P tile (+8 pad)

  const int tid  = threadIdx.x;
  const int lane = tid & 63;
  const int wave = tid >> 6;                 // 0..7
  const int l15  = lane & 15;
  const int l4   = lane >> 4;

  const int nqb  = Sc / QB;                  // 16
  const int head = blockIdx.x / nqb;         // b*H + h
  const int q0   = (blockIdx.x % nqb) * QB;
  const int b    = head / Hc;
  const int h    = head % Hc;

  const _Float16* qbase  = q  + ((size_t)head * Sc + q0 + wave * 16) * HDc;
  const _Float16* kbase  = k  + (size_t)head * Sc * HDc;
  const _Float16* vtbase = vt + (size_t)head * HDc * Sc;
  const float*    mbase  = mask + ((size_t)b * Sc + q0 + wave * 16) * Sc;
  const float*    mlane  = mbase + (size_t)l15 * Sc + l4 * 4;  // per-lane mask base

  const int srow  = tid >> 3;                // 0..63
  const int scol  = tid & 7;                 // 16B chunk col
  const int sofs  = srow * 64 + (scol ^ (srow & 7)) * 8;

  const int c0 = ((l4)     ^ (l15 & 7)) * 8;
  const int c1 = ((l4 + 4) ^ (l15 & 7)) * 8;

  f16x8 qf[2];
#pragma unroll
  for (int f = 0; f < 2; ++f)
    qf[f] = *reinterpret_cast<const f16x8*>(
        qbase + (size_t)l15 * HDc + l4 * 8 + 32 * f);

  f16x8 ones;
#pragma unroll
  for (int i = 0; i < 8; ++i) ones[i] = (_Float16)1.0f;

  f32x4 O[4];
#pragma unroll
  for (int dt = 0; dt < 4; ++dt) O[dt] = f32x4{0.f, 0.f, 0.f, 0.f};
  float m_q = -3e38f;
  float l_r[4];
#pragma unroll
  for (int r = 0; r < 4; ++r) l_r[r] = 0.f;

  // prologue: stage tile 0 K/V + prefetch mask tile 0 into registers
  *reinterpret_cast<uint4*>(&Ks[0][sofs]) =
      *reinterpret_cast<const uint4*>(kbase + (size_t)srow * HDc + scol * 8);
  *reinterpret_cast<uint4*>(&Vs[0][sofs]) =
      *reinterpret_cast<const uint4*>(vtbase + (size_t)srow * Sc + scol * 8);
  float4 mpf[4];
#pragma unroll
  for (int nt = 0; nt < 4; ++nt)
    mpf[nt] = *reinterpret_cast<const float4*>(mlane + 16 * nt);

  for (int kt = 0; kt < NT; ++kt) {
    const int k0 = kt * KB;
    const int cur = kt & 1, nxt = cur ^ 1;
    __syncthreads();

    uint4 kr, vr;
    const bool pf = (kt + 1) < NT;
    if (pf) {
      const int k1 = k0 + KB;
      kr = *reinterpret_cast<const uint4*>(kbase + (size_t)(k1 + srow) * HDc + scol * 8);
      vr = *reinterpret_cast<const uint4*>(vtbase + (size_t)srow * Sc + k1 + scol * 8);
    }

    f32x4 s[4];
    __builtin_amdgcn_s_setprio(1);
#pragma unroll
    for (int nt = 0; nt < 4; ++nt) {
      const int krow = (16 * nt + l15) * 64;
      f32x4 acc = f32x4{0.f, 0.f, 0.f, 0.f};
      acc = __builtin_amdgcn_mfma_f32_16x16x32_f16(
          *reinterpret_cast<const f16x8*>(&Ks[cur][krow + c0]), qf[0], acc, 0, 0, 0);
      acc = __builtin_amdgcn_mfma_f32_16x16x32_f16(
          *reinterpret_cast<const f16x8*>(&Ks[cur][krow + c1]), qf[1], acc, 0, 0, 0);
      s[nt] = acc;
    }
    __builtin_amdgcn_s_setprio(0);

    // + mask from the prefetched registers, then immediately re-prefetch t+1
#pragma unroll
    for (int nt = 0; nt < 4; ++nt) {
      s[nt][0] += mpf[nt].x; s[nt][1] += mpf[nt].y;
      s[nt][2] += mpf[nt].z; s[nt][3] += mpf[nt].w;
    }
    if (pf) {
#pragma unroll
      for (int nt = 0; nt < 4; ++nt)
        mpf[nt] = *reinterpret_cast<const float4*>(mlane + (k0 + KB) + 16 * nt);
    }

    float lm = s[0][0];
#pragma unroll
    for (int nt = 0; nt < 4; ++nt)
#pragma unroll
      for (int reg = 0; reg < 4; ++reg) lm = fmaxf(lm, s[nt][reg]);

    if (!__all(lm - m_q <= 8.0f)) {
      float vm = fmaxf(lm, __shfl_xor(lm, 16));
      vm = fmaxf(vm, __shfl_xor(vm, 32));
      float mn = fmaxf(m_q, vm);
      float cc = __expf(m_q - mn);
      m_q = mn;
#pragma unroll
      for (int reg = 0; reg < 4; ++reg) {
        float ccq = __shfl(cc, l4 * 4 + reg);
        l_r[reg] *= ccq;
#pragma unroll
        for (int dt = 0; dt < 4; ++dt) O[dt][reg] *= ccq;
      }
    }

#pragma unroll
    for (int nt = 0; nt < 4; ++nt) {
      float p0 = __expf(s[nt][0] - m_q);
      float p1 = __expf(s[nt][1] - m_q);
      float p2 = __expf(s[nt][2] - m_q);
      float p3 = __expf(s[nt][3] - m_q);
      union { uint2 u; fp16v2 h[2]; } pk;
      pk.h[0] = __builtin_amdgcn_cvt_pkrtz(p0, p1);
      pk.h[1] = __builtin_amdgcn_cvt_pkrtz(p2, p3);
      *reinterpret_cast<uint2*>(&Ps[wave][l15][16 * nt + l4 * 4]) = pk.u;
    }

    asm volatile("" ::: "memory");

    f16x8 pa0 = *reinterpret_cast<const f16x8*>(&Ps[wave][l15][l4 * 8]);
    f16x8 pa1 = *reinterpret_cast<const f16x8*>(&Ps[wave][l15][l4 * 8 + 32]);

    __builtin_amdgcn_s_setprio(1);
    f32x4 lacc = f32x4{0.f, 0.f, 0.f, 0.f};
    lacc = __builtin_amdgcn_mfma_f32_16x16x32_f16(pa0, ones, lacc, 0, 0, 0);
    lacc = __builtin_amdgcn_mfma_f32_16x16x32_f16(pa1, ones, lacc, 0, 0, 0);

#pragma unroll
    for (int dt = 0; dt < 4; ++dt) {
      const int vrow = (16 * dt + l15) * 64;
      O[dt] = __builtin_amdgcn_mfma_f32_16x16x32_f16(
          pa0, *reinterpret_cast<const f16x8*>(&Vs[cur][vrow + c0]), O[dt], 0, 0, 0);
      O[dt] = __builtin_amdgcn_mfma_f32_16x16x32_f16(
          pa1, *reinterpret_cast<const f16x8*>(&Vs[cur][vrow + c1]), O[dt], 0, 0, 0);
    }
    __builtin_amdgcn_s_setprio(0);

#pragma unroll
    for (int reg = 0; reg < 4; ++reg) l_r[reg] += lacc[reg];

    if (pf) {
      *reinterpret_cast<uint4*>(&Ks[nxt][sofs]) = kr;
      *reinterpret_cast<uint4*>(&Vs[nxt][sofs]) = vr;
    }
  }

  float inv[4];
#pragma unroll
  for (int reg = 0; reg < 4; ++reg) inv[reg] = 1.0f / l_r[reg];
#pragma unroll
  for (int dt = 0; dt < 4; ++dt)
#pragma unroll
    for (int reg = 0; reg < 4; ++reg) {
      int row = q0 + wave * 16 + l4 * 4 + reg;
      size_t addr = ((size_t)b * Sc + row) * Dc + h * HDc + l15 + 16 * dt;
      float val = O[dt][reg] * inv[reg];
      _Float16 hh = (_Float16)val;
      ctxh[addr] = hh;
      ctxl[addr] = (_Float16)(val - (float)hh);
    }
}

// ---------------------------------------------------------------------------
extern "C" void kernel_launch(void* const* d_in, const int* in_sizes, int n_in,
                              void* d_out, int out_size, void* d_ws, size_t ws_size,
                              hipStream_t stream) {
  const float* feats = (const float*)d_in[0];
  const float* mask  = (const float*)d_in[1];
  const float* wq    = (const float*)d_in[2];
  const float* bq    = (const float*)d_in[3];
  const float* wk    = (const float*)d_in[4];
  const float* bk    = (const float*)d_in[5];
  const float* wv    = (const float*)d_in[6];
  const float* bv    = (const float*)d_in[7];
  const float* wo    = (const float*)d_in[8];
  const float* bo    = (const float*)d_in[9];

  char* ws = (char*)d_ws;
  const size_t MB = (size_t)1 << 20;
  _Float16* fh   = (_Float16*)(ws);             // 8 MB
  _Float16* fl   = (_Float16*)(ws + 8  * MB);   // 8 MB
  _Float16* wh3  = (_Float16*)(ws + 16 * MB);   // 6 MB  [wq;wk;wv] hi
  _Float16* wl3  = (_Float16*)(ws + 22 * MB);   // 6 MB  [wq;wk;wv] lo
  _Float16* woh  = (_Float16*)(ws + 28 * MB);   // 2 MB
  _Float16* wol  = (_Float16*)(ws + 30 * MB);   // 2 MB
  _Float16* qb   = (_Float16*)(ws + 32 * MB);   // 8 MB
  _Float16* kb   = (_Float16*)(ws + 40 * MB);   // 8 MB
  _Float16* vtb  = (_Float16*)(ws + 48 * MB);   // 8 MB
  _Float16* ctxh = (_Float16*)(ws + 56 * MB);   // 8 MB
  _Float16* ctxl = (_Float16*)(ws + 64 * MB);   // 8 MB -> 72 MB total

  float* out   = (float*)d_out;
  float* gated = out + 4194304;

  split5<<<8192, 256, 0, stream>>>(feats, wq, wk, wv, wo,
                                   fh, fl, wh3, wl3, woh, wol);

  gemm_qkv<<<dim3(NROWS / 128, 3072 / 128), 256, 0, stream>>>(
      fh, fl, wh3, wl3, bq, bk, bv, qb, kb, vtb);

  attn_mfma<<<Bc * Hc * (Sc / QB), 512, 0, stream>>>(qb, kb, vtb, mask, ctxh, ctxl);

  gemm_wo<<<dim3(NROWS / 64, Dc / 128), 256, 0, stream>>>(
      ctxh, ctxl, woh, wol, bo, out, gated, feats);
}

// Round 12
// 160.040 us; speedup vs baseline: 2.1258x; 1.3049x over previous
//
#include <hip/hip_runtime.h>
#include <math.h>

#define Bc 2
#define Sc 2048
#define Dc 1024
#define Hc 16
#define HDc 64
#define NROWS 4096  // B*S

typedef __attribute__((ext_vector_type(8))) _Float16 f16x8;
typedef __attribute__((ext_vector_type(4))) _Float16 f16x4;
typedef __attribute__((ext_vector_type(2))) __fp16 fp16v2;
typedef __attribute__((ext_vector_type(4))) float f32x4;

// ---------------------------------------------------------------------------
// Fused 5-way fp32 -> f16 convert (feats, wq, wk, wv, wo). Pure f16 (no lo).
// wq/wk/wv land packed into wh3 = [wq; wk; wv] (3072 x 1024).
// ---------------------------------------------------------------------------
__global__ __launch_bounds__(256)
void cvt5(const float* __restrict__ f,  const float* __restrict__ wq,
          const float* __restrict__ wk, const float* __restrict__ wv,
          const float* __restrict__ wo_,
          _Float16* __restrict__ fh, _Float16* __restrict__ wh3,
          _Float16* __restrict__ woh)
{
  int blk = blockIdx.x;
  const float* src; _Float16* hi; int base;
  if (blk < 4096)      { src = f;   hi = fh;            base = blk; }
  else if (blk < 5120) { src = wq;  hi = wh3;           base = blk - 4096; }
  else if (blk < 6144) { src = wk;  hi = wh3 + 1048576; base = blk - 5120; }
  else if (blk < 7168) { src = wv;  hi = wh3 + 2097152; base = blk - 6144; }
  else                 { src = wo_; hi = woh;           base = blk - 7168; }
  int i = base * 256 + threadIdx.x;
  float4 v = reinterpret_cast<const float4*>(src)[i];
  f16x4 h;
  h[0] = (_Float16)v.x; h[1] = (_Float16)v.y;
  h[2] = (_Float16)v.z; h[3] = (_Float16)v.w;
  reinterpret_cast<f16x4*>(hi)[i] = h;
}

// ---------------------------------------------------------------------------
// Fused QKV f16 GEMM (1 MFMA). A=[4096,1024], W=[3072,1024].
// grid (32, 24) of 128x128 tiles; LDS 20 KB -> 4 blocks/CU.
// ---------------------------------------------------------------------------
__global__ __launch_bounds__(256, 4)
void gemm_qkv(const _Float16* __restrict__ Ah, const _Float16* __restrict__ Wh,
              const float* __restrict__ bq, const float* __restrict__ bk,
              const float* __restrict__ bv,
              _Float16* __restrict__ qb, _Float16* __restrict__ kb,
              _Float16* __restrict__ vtb)
{
  __shared__ _Float16 Ash[128][40];
  __shared__ _Float16 Wsh[128][40];

  const int tid  = threadIdx.x;
  const int lane = tid & 63, wid = tid >> 6;
  const int l15  = lane & 15, l4 = lane >> 4;
  const int wr   = wid >> 1, wc = wid & 1;     // wave tile 64x64
  const int arow0 = blockIdx.x * 128;
  const int wrow0 = blockIdx.y * 128;

  f32x4 acc[4][4];
#pragma unroll
  for (int m = 0; m < 4; ++m)
#pragma unroll
    for (int n = 0; n < 4; ++n) acc[m][n] = f32x4{0.f, 0.f, 0.f, 0.f};

  for (int k0 = 0; k0 < Dc; k0 += 32) {
    __syncthreads();
#pragma unroll
    for (int p = 0; p < 2; ++p) {
      int e = tid + 256 * p;
      int r = e >> 2, c8 = (e & 3) * 8;
      *reinterpret_cast<uint4*>(&Ash[r][c8]) =
          *reinterpret_cast<const uint4*>(Ah + (size_t)(arow0 + r) * Dc + k0 + c8);
      *reinterpret_cast<uint4*>(&Wsh[r][c8]) =
          *reinterpret_cast<const uint4*>(Wh + (size_t)(wrow0 + r) * Dc + k0 + c8);
    }
    __syncthreads();

    f16x8 bh[4];
#pragma unroll
    for (int n = 0; n < 4; ++n)
      bh[n] = *reinterpret_cast<const f16x8*>(&Wsh[wc * 64 + n * 16 + l15][l4 * 8]);
#pragma unroll
    for (int m = 0; m < 4; ++m) {
      f16x8 ah = *reinterpret_cast<const f16x8*>(&Ash[wr * 64 + m * 16 + l15][l4 * 8]);
#pragma unroll
      for (int n = 0; n < 4; ++n)
        acc[m][n] = __builtin_amdgcn_mfma_f32_16x16x32_f16(ah, bh[n], acc[m][n], 0, 0, 0);
    }
  }

  // epilogue
#pragma unroll
  for (int m = 0; m < 4; ++m) {
#pragma unroll
    for (int n = 0; n < 4; ++n) {
      int cbase = wrow0 + wc * 64 + n * 16;      // 16-aligned, never crosses 1024
      int seg = cbase >> 10;                     // 0=q, 1=k, 2=v
      int o = (cbase & 1023) + l15;
      int h = o >> 6, hd = o & 63;
      const float* bias = (seg == 0) ? bq : ((seg == 1) ? bk : bv);
      float bval = bias[o];
      float alpha = (seg == 0) ? 0.125f : 1.0f;
      int r0 = arow0 + wr * 64 + m * 16 + l4 * 4;
      int b = r0 >> 11, s0 = r0 & (Sc - 1);
      if (seg == 2) {
        f16x4 pk;
#pragma unroll
        for (int reg = 0; reg < 4; ++reg)
          pk[reg] = (_Float16)((acc[m][n][reg] + bval) * alpha);
        *reinterpret_cast<f16x4*>(
            &vtb[(((size_t)b * Hc + h) * HDc + hd) * Sc + s0]) = pk;
      } else {
        _Float16* dst = (seg == 0) ? qb : kb;
#pragma unroll
        for (int reg = 0; reg < 4; ++reg) {
          float val = (acc[m][n][reg] + bval) * alpha;
          dst[(((size_t)b * Hc + h) * Sc + (s0 + reg)) * HDc + hd] = (_Float16)val;
        }
      }
    }
  }
}

// ---------------------------------------------------------------------------
// Output GEMM, f16 1-MFMA: 64x128 blocks, grid (64,8); LDS 15 KB -> 4/CU.
// out1 = (ctx@wo^T + bo) (gated); out0 = feats * out1 (out).
// ---------------------------------------------------------------------------
__global__ __launch_bounds__(256, 4)
void gemm_wo(const _Float16* __restrict__ Ah, const _Float16* __restrict__ Wh,
             const float* __restrict__ bias,
             float* __restrict__ out0, float* __restrict__ out1,
             const float* __restrict__ feats)
{
  __shared__ _Float16 Ash[64][40];
  __shared__ _Float16 Wsh[128][40];

  const int tid  = threadIdx.x;
  const int lane = tid & 63, wid = tid >> 6;
  const int l15  = lane & 15, l4 = lane >> 4;
  const int wr   = wid >> 1, wc = wid & 1;     // wave tile 32x64
  const int arow0 = blockIdx.x * 64;
  const int wrow0 = blockIdx.y * 128;

  f32x4 acc[2][4];
#pragma unroll
  for (int m = 0; m < 2; ++m)
#pragma unroll
    for (int n = 0; n < 4; ++n) acc[m][n] = f32x4{0.f, 0.f, 0.f, 0.f};

  for (int k0 = 0; k0 < Dc; k0 += 32) {
    __syncthreads();
    {
      int r = tid >> 2, c8 = (tid & 3) * 8;
      *reinterpret_cast<uint4*>(&Ash[r][c8]) =
          *reinterpret_cast<const uint4*>(Ah + (size_t)(arow0 + r) * Dc + k0 + c8);
    }
#pragma unroll
    for (int p = 0; p < 2; ++p) {
      int e = tid + 256 * p;
      int r = e >> 2, c8 = (e & 3) * 8;
      *reinterpret_cast<uint4*>(&Wsh[r][c8]) =
          *reinterpret_cast<const uint4*>(Wh + (size_t)(wrow0 + r) * Dc + k0 + c8);
    }
    __syncthreads();

    f16x8 bh[4];
#pragma unroll
    for (int n = 0; n < 4; ++n)
      bh[n] = *reinterpret_cast<const f16x8*>(&Wsh[wc * 64 + n * 16 + l15][l4 * 8]);
#pragma unroll
    for (int m = 0; m < 2; ++m) {
      f16x8 ah = *reinterpret_cast<const f16x8*>(&Ash[wr * 32 + m * 16 + l15][l4 * 8]);
#pragma unroll
      for (int n = 0; n < 4; ++n)
        acc[m][n] = __builtin_amdgcn_mfma_f32_16x16x32_f16(ah, bh[n], acc[m][n], 0, 0, 0);
    }
  }

#pragma unroll
  for (int m = 0; m < 2; ++m) {
#pragma unroll
    for (int n = 0; n < 4; ++n) {
      int c = wrow0 + wc * 64 + n * 16 + l15;
      float bval = bias[c];
#pragma unroll
      for (int reg = 0; reg < 4; ++reg) {
        int r = arow0 + wr * 32 + m * 16 + l4 * 4 + reg;
        float val = acc[m][n][reg] + bval;
        out1[(size_t)r * Dc + c] = val;
        out0[(size_t)r * Dc + c] = feats[(size_t)r * Dc + c] * val;
      }
    }
  }
}

// ---------------------------------------------------------------------------
// Flash attention, f16 MFMA (round-11 structure; ctx written as f16 only).
// ---------------------------------------------------------------------------
#define QB 128
#define KB 64
#define NT (Sc / KB)

__global__ __launch_bounds__(512, 4)
void attn_mfma(const _Float16* __restrict__ q,
               const _Float16* __restrict__ k,
               const _Float16* __restrict__ vt,
               const float* __restrict__ mask,
               _Float16* __restrict__ ctxh)
{
  __shared__ _Float16 Ks[2][KB * 64];        // linear, XOR-swizzled
  __shared__ _Float16 Vs[2][HDc * 64];       // linear, XOR-swizzled
  __shared__ _Float16 Ps[8][16][72];         // per-wave P tile (+8 pad)

  const int tid  = threadIdx.x;
  const int lane = tid & 63;
  const int wave = tid >> 6;                 // 0..7
  const int l15  = lane & 15;
  const int l4   = lane >> 4;

  const int nqb  = Sc / QB;                  // 16
  const int head = blockIdx.x / nqb;         // b*H + h
  const int q0   = (blockIdx.x % nqb) * QB;
  const int b    = head / Hc;
  const int h    = head % Hc;

  const _Float16* qbase  = q  + ((size_t)head * Sc + q0 + wave * 16) * HDc;
  const _Float16* kbase  = k  + (size_t)head * Sc * HDc;
  const _Float16* vtbase = vt + (size_t)head * HDc * Sc;
  const float*    mbase  = mask + ((size_t)b * Sc + q0 + wave * 16) * Sc;
  const float*    mlane  = mbase + (size_t)l15 * Sc + l4 * 4;

  const int srow  = tid >> 3;                // 0..63
  const int scol  = tid & 7;                 // 16B chunk col
  const int sofs  = srow * 64 + (scol ^ (srow & 7)) * 8;

  const int c0 = ((l4)     ^ (l15 & 7)) * 8;
  const int c1 = ((l4 + 4) ^ (l15 & 7)) * 8;

  f16x8 qf[2];
#pragma unroll
  for (int f = 0; f < 2; ++f)
    qf[f] = *reinterpret_cast<const f16x8*>(
        qbase + (size_t)l15 * HDc + l4 * 8 + 32 * f);

  f16x8 ones;
#pragma unroll
  for (int i = 0; i < 8; ++i) ones[i] = (_Float16)1.0f;

  f32x4 O[4];
#pragma unroll
  for (int dt = 0; dt < 4; ++dt) O[dt] = f32x4{0.f, 0.f, 0.f, 0.f};
  float m_q = -3e38f;
  float l_r[4];
#pragma unroll
  for (int r = 0; r < 4; ++r) l_r[r] = 0.f;

  *reinterpret_cast<uint4*>(&Ks[0][sofs]) =
      *reinterpret_cast<const uint4*>(kbase + (size_t)srow * HDc + scol * 8);
  *reinterpret_cast<uint4*>(&Vs[0][sofs]) =
      *reinterpret_cast<const uint4*>(vtbase + (size_t)srow * Sc + scol * 8);
  float4 mpf[4];
#pragma unroll
  for (int nt = 0; nt < 4; ++nt)
    mpf[nt] = *reinterpret_cast<const float4*>(mlane + 16 * nt);

  for (int kt = 0; kt < NT; ++kt) {
    const int k0 = kt * KB;
    const int cur = kt & 1, nxt = cur ^ 1;
    __syncthreads();

    uint4 kr, vr;
    const bool pf = (kt + 1) < NT;
    if (pf) {
      const int k1 = k0 + KB;
      kr = *reinterpret_cast<const uint4*>(kbase + (size_t)(k1 + srow) * HDc + scol * 8);
      vr = *reinterpret_cast<const uint4*>(vtbase + (size_t)srow * Sc + k1 + scol * 8);
    }

    f32x4 s[4];
    __builtin_amdgcn_s_setprio(1);
#pragma unroll
    for (int nt = 0; nt < 4; ++nt) {
      const int krow = (16 * nt + l15) * 64;
      f32x4 acc = f32x4{0.f, 0.f, 0.f, 0.f};
      acc = __builtin_amdgcn_mfma_f32_16x16x32_f16(
          *reinterpret_cast<const f16x8*>(&Ks[cur][krow + c0]), qf[0], acc, 0, 0, 0);
      acc = __builtin_amdgcn_mfma_f32_16x16x32_f16(
          *reinterpret_cast<const f16x8*>(&Ks[cur][krow + c1]), qf[1], acc, 0, 0, 0);
      s[nt] = acc;
    }
    __builtin_amdgcn_s_setprio(0);

#pragma unroll
    for (int nt = 0; nt < 4; ++nt) {
      s[nt][0] += mpf[nt].x; s[nt][1] += mpf[nt].y;
      s[nt][2] += mpf[nt].z; s[nt][3] += mpf[nt].w;
    }
    if (pf) {
#pragma unroll
      for (int nt = 0; nt < 4; ++nt)
        mpf[nt] = *reinterpret_cast<const float4*>(mlane + (k0 + KB) + 16 * nt);
    }

    float lm = s[0][0];
#pragma unroll
    for (int nt = 0; nt < 4; ++nt)
#pragma unroll
      for (int reg = 0; reg < 4; ++reg) lm = fmaxf(lm, s[nt][reg]);

    if (!__all(lm - m_q <= 8.0f)) {
      float vm = fmaxf(lm, __shfl_xor(lm, 16));
      vm = fmaxf(vm, __shfl_xor(vm, 32));
      float mn = fmaxf(m_q, vm);
      float cc = __expf(m_q - mn);
      m_q = mn;
#pragma unroll
      for (int reg = 0; reg < 4; ++reg) {
        float ccq = __shfl(cc, l4 * 4 + reg);
        l_r[reg] *= ccq;
#pragma unroll
        for (int dt = 0; dt < 4; ++dt) O[dt][reg] *= ccq;
      }
    }

#pragma unroll
    for (int nt = 0; nt < 4; ++nt) {
      float p0 = __expf(s[nt][0] - m_q);
      float p1 = __expf(s[nt][1] - m_q);
      float p2 = __expf(s[nt][2] - m_q);
      float p3 = __expf(s[nt][3] - m_q);
      union { uint2 u; fp16v2 h[2]; } pk;
      pk.h[0] = __builtin_amdgcn_cvt_pkrtz(p0, p1);
      pk.h[1] = __builtin_amdgcn_cvt_pkrtz(p2, p3);
      *reinterpret_cast<uint2*>(&Ps[wave][l15][16 * nt + l4 * 4]) = pk.u;
    }

    asm volatile("" ::: "memory");

    f16x8 pa0 = *reinterpret_cast<const f16x8*>(&Ps[wave][l15][l4 * 8]);
    f16x8 pa1 = *reinterpret_cast<const f16x8*>(&Ps[wave][l15][l4 * 8 + 32]);

    __builtin_amdgcn_s_setprio(1);
    f32x4 lacc = f32x4{0.f, 0.f, 0.f, 0.f};
    lacc = __builtin_amdgcn_mfma_f32_16x16x32_f16(pa0, ones, lacc, 0, 0, 0);
    lacc = __builtin_amdgcn_mfma_f32_16x16x32_f16(pa1, ones, lacc, 0, 0, 0);

#pragma unroll
    for (int dt = 0; dt < 4; ++dt) {
      const int vrow = (16 * dt + l15) * 64;
      O[dt] = __builtin_amdgcn_mfma_f32_16x16x32_f16(
          pa0, *reinterpret_cast<const f16x8*>(&Vs[cur][vrow + c0]), O[dt], 0, 0, 0);
      O[dt] = __builtin_amdgcn_mfma_f32_16x16x32_f16(
          pa1, *reinterpret_cast<const f16x8*>(&Vs[cur][vrow + c1]), O[dt], 0, 0, 0);
    }
    __builtin_amdgcn_s_setprio(0);

#pragma unroll
    for (int reg = 0; reg < 4; ++reg) l_r[reg] += lacc[reg];

    if (pf) {
      *reinterpret_cast<uint4*>(&Ks[nxt][sofs]) = kr;
      *reinterpret_cast<uint4*>(&Vs[nxt][sofs]) = vr;
    }
  }

  float inv[4];
#pragma unroll
  for (int reg = 0; reg < 4; ++reg) inv[reg] = 1.0f / l_r[reg];
#pragma unroll
  for (int dt = 0; dt < 4; ++dt)
#pragma unroll
    for (int reg = 0; reg < 4; ++reg) {
      int row = q0 + wave * 16 + l4 * 4 + reg;
      size_t addr = ((size_t)b * Sc + row) * Dc + h * HDc + l15 + 16 * dt;
      ctxh[addr] = (_Float16)(O[dt][reg] * inv[reg]);
    }
}

// ---------------------------------------------------------------------------
extern "C" void kernel_launch(void* const* d_in, const int* in_sizes, int n_in,
                              void* d_out, int out_size, void* d_ws, size_t ws_size,
                              hipStream_t stream) {
  const float* feats = (const float*)d_in[0];
  const float* mask  = (const float*)d_in[1];
  const float* wq    = (const float*)d_in[2];
  const float* bq    = (const float*)d_in[3];
  const float* wk    = (const float*)d_in[4];
  const float* bk    = (const float*)d_in[5];
  const float* wv    = (const float*)d_in[6];
  const float* bv    = (const float*)d_in[7];
  const float* wo    = (const float*)d_in[8];
  const float* bo    = (const float*)d_in[9];

  char* ws = (char*)d_ws;
  const size_t MB = (size_t)1 << 20;
  _Float16* fh   = (_Float16*)(ws);             // 8 MB
  _Float16* wh3  = (_Float16*)(ws + 8  * MB);   // 6 MB  [wq;wk;wv]
  _Float16* woh  = (_Float16*)(ws + 14 * MB);   // 2 MB
  _Float16* qb   = (_Float16*)(ws + 16 * MB);   // 8 MB
  _Float16* kb   = (_Float16*)(ws + 24 * MB);   // 8 MB
  _Float16* vtb  = (_Float16*)(ws + 32 * MB);   // 8 MB
  _Float16* ctxh = (_Float16*)(ws + 40 * MB);   // 8 MB -> 48 MB total

  float* out   = (float*)d_out;
  float* gated = out + 4194304;

  cvt5<<<8192, 256, 0, stream>>>(feats, wq, wk, wv, wo, fh, wh3, woh);

  gemm_qkv<<<dim3(NROWS / 128, 3072 / 128), 256, 0, stream>>>(
      fh, wh3, bq, bk, bv, qb, kb, vtb);

  attn_mfma<<<Bc * Hc * (Sc / QB), 512, 0, stream>>>(qb, kb, vtb, mask, ctxh);

  gemm_wo<<<dim3(NROWS / 64, Dc / 128), 256, 0, stream>>>(
      ctxh, woh, bo, out, gated, feats);
}

// Round 13
// 159.098 us; speedup vs baseline: 2.1384x; 1.0059x over previous
//
#include <hip/hip_runtime.h>
#include <math.h>

#define Bc 2
#define Sc 2048
#define Dc 1024
#define Hc 16
#define HDc 64
#define NROWS 4096  // B*S

typedef __attribute__((ext_vector_type(8))) _Float16 f16x8;
typedef __attribute__((ext_vector_type(4))) _Float16 f16x4;
typedef __attribute__((ext_vector_type(2))) __fp16 fp16v2;
typedef __attribute__((ext_vector_type(4))) float f32x4;
typedef __attribute__((ext_vector_type(16))) float f32x16;

// ---------------------------------------------------------------------------
// Fused 5-way fp32 -> f16 convert (feats, wq, wk, wv, wo).
// wq/wk/wv land packed into wh3 = [wq; wk; wv] (3072 x 1024).
// ---------------------------------------------------------------------------
__global__ __launch_bounds__(256)
void cvt5(const float* __restrict__ f,  const float* __restrict__ wq,
          const float* __restrict__ wk, const float* __restrict__ wv,
          const float* __restrict__ wo_,
          _Float16* __restrict__ fh, _Float16* __restrict__ wh3,
          _Float16* __restrict__ woh)
{
  int blk = blockIdx.x;
  const float* src; _Float16* hi; int base;
  if (blk < 4096)      { src = f;   hi = fh;            base = blk; }
  else if (blk < 5120) { src = wq;  hi = wh3;           base = blk - 4096; }
  else if (blk < 6144) { src = wk;  hi = wh3 + 1048576; base = blk - 5120; }
  else if (blk < 7168) { src = wv;  hi = wh3 + 2097152; base = blk - 6144; }
  else                 { src = wo_; hi = woh;           base = blk - 7168; }
  int i = base * 256 + threadIdx.x;
  float4 v = reinterpret_cast<const float4*>(src)[i];
  f16x4 h;
  h[0] = (_Float16)v.x; h[1] = (_Float16)v.y;
  h[2] = (_Float16)v.z; h[3] = (_Float16)v.w;
  reinterpret_cast<f16x4*>(hi)[i] = h;
}

// ---------------------------------------------------------------------------
// Fused QKV f16 GEMM (1 MFMA). A=[4096,1024], W=[3072,1024]. (unchanged)
// ---------------------------------------------------------------------------
__global__ __launch_bounds__(256, 4)
void gemm_qkv(const _Float16* __restrict__ Ah, const _Float16* __restrict__ Wh,
              const float* __restrict__ bq, const float* __restrict__ bk,
              const float* __restrict__ bv,
              _Float16* __restrict__ qb, _Float16* __restrict__ kb,
              _Float16* __restrict__ vtb)
{
  __shared__ _Float16 Ash[128][40];
  __shared__ _Float16 Wsh[128][40];

  const int tid  = threadIdx.x;
  const int lane = tid & 63, wid = tid >> 6;
  const int l15  = lane & 15, l4 = lane >> 4;
  const int wr   = wid >> 1, wc = wid & 1;     // wave tile 64x64
  const int arow0 = blockIdx.x * 128;
  const int wrow0 = blockIdx.y * 128;

  f32x4 acc[4][4];
#pragma unroll
  for (int m = 0; m < 4; ++m)
#pragma unroll
    for (int n = 0; n < 4; ++n) acc[m][n] = f32x4{0.f, 0.f, 0.f, 0.f};

  for (int k0 = 0; k0 < Dc; k0 += 32) {
    __syncthreads();
#pragma unroll
    for (int p = 0; p < 2; ++p) {
      int e = tid + 256 * p;
      int r = e >> 2, c8 = (e & 3) * 8;
      *reinterpret_cast<uint4*>(&Ash[r][c8]) =
          *reinterpret_cast<const uint4*>(Ah + (size_t)(arow0 + r) * Dc + k0 + c8);
      *reinterpret_cast<uint4*>(&Wsh[r][c8]) =
          *reinterpret_cast<const uint4*>(Wh + (size_t)(wrow0 + r) * Dc + k0 + c8);
    }
    __syncthreads();

    f16x8 bh[4];
#pragma unroll
    for (int n = 0; n < 4; ++n)
      bh[n] = *reinterpret_cast<const f16x8*>(&Wsh[wc * 64 + n * 16 + l15][l4 * 8]);
#pragma unroll
    for (int m = 0; m < 4; ++m) {
      f16x8 ah = *reinterpret_cast<const f16x8*>(&Ash[wr * 64 + m * 16 + l15][l4 * 8]);
#pragma unroll
      for (int n = 0; n < 4; ++n)
        acc[m][n] = __builtin_amdgcn_mfma_f32_16x16x32_f16(ah, bh[n], acc[m][n], 0, 0, 0);
    }
  }

  // epilogue
#pragma unroll
  for (int m = 0; m < 4; ++m) {
#pragma unroll
    for (int n = 0; n < 4; ++n) {
      int cbase = wrow0 + wc * 64 + n * 16;      // 16-aligned, never crosses 1024
      int seg = cbase >> 10;                     // 0=q, 1=k, 2=v
      int o = (cbase & 1023) + l15;
      int h = o >> 6, hd = o & 63;
      const float* bias = (seg == 0) ? bq : ((seg == 1) ? bk : bv);
      float bval = bias[o];
      float alpha = (seg == 0) ? 0.125f : 1.0f;
      int r0 = arow0 + wr * 64 + m * 16 + l4 * 4;
      int b = r0 >> 11, s0 = r0 & (Sc - 1);
      if (seg == 2) {
        f16x4 pk;
#pragma unroll
        for (int reg = 0; reg < 4; ++reg)
          pk[reg] = (_Float16)((acc[m][n][reg] + bval) * alpha);
        *reinterpret_cast<f16x4*>(
            &vtb[(((size_t)b * Hc + h) * HDc + hd) * Sc + s0]) = pk;
      } else {
        _Float16* dst = (seg == 0) ? qb : kb;
#pragma unroll
        for (int reg = 0; reg < 4; ++reg) {
          float val = (acc[m][n][reg] + bval) * alpha;
          dst[(((size_t)b * Hc + h) * Sc + (s0 + reg)) * HDc + hd] = (_Float16)val;
        }
      }
    }
  }
}

// ---------------------------------------------------------------------------
// Output GEMM, f16 1-MFMA (unchanged).
// ---------------------------------------------------------------------------
__global__ __launch_bounds__(256, 4)
void gemm_wo(const _Float16* __restrict__ Ah, const _Float16* __restrict__ Wh,
             const float* __restrict__ bias,
             float* __restrict__ out0, float* __restrict__ out1,
             const float* __restrict__ feats)
{
  __shared__ _Float16 Ash[64][40];
  __shared__ _Float16 Wsh[128][40];

  const int tid  = threadIdx.x;
  const int lane = tid & 63, wid = tid >> 6;
  const int l15  = lane & 15, l4 = lane >> 4;
  const int wr   = wid >> 1, wc = wid & 1;     // wave tile 32x64
  const int arow0 = blockIdx.x * 64;
  const int wrow0 = blockIdx.y * 128;

  f32x4 acc[2][4];
#pragma unroll
  for (int m = 0; m < 2; ++m)
#pragma unroll
    for (int n = 0; n < 4; ++n) acc[m][n] = f32x4{0.f, 0.f, 0.f, 0.f};

  for (int k0 = 0; k0 < Dc; k0 += 32) {
    __syncthreads();
    {
      int r = tid >> 2, c8 = (tid & 3) * 8;
      *reinterpret_cast<uint4*>(&Ash[r][c8]) =
          *reinterpret_cast<const uint4*>(Ah + (size_t)(arow0 + r) * Dc + k0 + c8);
    }
#pragma unroll
    for (int p = 0; p < 2; ++p) {
      int e = tid + 256 * p;
      int r = e >> 2, c8 = (e & 3) * 8;
      *reinterpret_cast<uint4*>(&Wsh[r][c8]) =
          *reinterpret_cast<const uint4*>(Wh + (size_t)(wrow0 + r) * Dc + k0 + c8);
    }
    __syncthreads();

    f16x8 bh[4];
#pragma unroll
    for (int n = 0; n < 4; ++n)
      bh[n] = *reinterpret_cast<const f16x8*>(&Wsh[wc * 64 + n * 16 + l15][l4 * 8]);
#pragma unroll
    for (int m = 0; m < 2; ++m) {
      f16x8 ah = *reinterpret_cast<const f16x8*>(&Ash[wr * 32 + m * 16 + l15][l4 * 8]);
#pragma unroll
      for (int n = 0; n < 4; ++n)
        acc[m][n] = __builtin_amdgcn_mfma_f32_16x16x32_f16(ah, bh[n], acc[m][n], 0, 0, 0);
    }
  }

#pragma unroll
  for (int m = 0; m < 2; ++m) {
#pragma unroll
    for (int n = 0; n < 4; ++n) {
      int c = wrow0 + wc * 64 + n * 16 + l15;
      float bval = bias[c];
#pragma unroll
      for (int reg = 0; reg < 4; ++reg) {
        int r = arow0 + wr * 32 + m * 16 + l4 * 4 + reg;
        float val = acc[m][n][reg] + bval;
        out1[(size_t)r * Dc + c] = val;
        out0[(size_t)r * Dc + c] = feats[(size_t)r * Dc + c] * val;
      }
    }
  }
}

// ---------------------------------------------------------------------------
// Flash attention, 32x32x16 f16 MFMA. Block = 4 waves; wave owns 32 q-rows
// (QB=128). Swapped QK^T: lane owns q-row (l&31). P built IN REGISTERS via
// cvt_pkrtz + v_permlane32_swap_b32 (no P LDS round-trip). Row sums via
// ones-MFMA land in O layout (no cross-lane epilogue). Defer-max (THR=8).
// K/V XOR-swizzled double-buffered LDS, mask register-prefetch.
// ---------------------------------------------------------------------------
#define QB 128
#define KB 64
#define NT (Sc / KB)

__global__ __launch_bounds__(256, 2)
void attn_mfma(const _Float16* __restrict__ q,
               const _Float16* __restrict__ k,
               const _Float16* __restrict__ vt,
               const float* __restrict__ mask,
               _Float16* __restrict__ ctxh)
{
  __shared__ _Float16 Ks[2][KB * 64];        // [k-row][hd], XOR-swizzled
  __shared__ _Float16 Vs[2][HDc * 64];       // V^T [d][k], XOR-swizzled

  const int tid  = threadIdx.x;
  const int lane = tid & 63;
  const int wq   = tid >> 6;                 // wave 0..3
  const int l31  = lane & 31;
  const int hi   = lane >> 5;

  const int nqb  = Sc / QB;                  // 16
  const int head = blockIdx.x / nqb;
  const int q0   = (blockIdx.x % nqb) * QB;
  const int b    = head / Hc;
  const int h    = head % Hc;

  const _Float16* kbase  = k  + (size_t)head * Sc * HDc;
  const _Float16* vtbase = vt + (size_t)head * HDc * Sc;
  const _Float16* qbase  = q  + ((size_t)head * Sc + q0 + wq * 32 + l31) * HDc;
  const float*    ml     = mask + ((size_t)b * Sc + q0 + wq * 32 + l31) * Sc + 4 * hi;

  // staging: 256 thr x 2 chunks each for K and V (chunk = 8 f16 = 16B)
  const int r0s = tid >> 3, cs = tid & 7;
  const int r1s = r0s + 32;
  const int so0 = r0s * 64 + ((cs ^ (r0s & 7)) * 8);
  const int so1 = r1s * 64 + ((cs ^ (r1s & 7)) * 8);

  // Q B-frags: lane holds col q=l31, k-dim hd = 16c + hi*8 + i
  f16x8 qf[4];
#pragma unroll
  for (int c = 0; c < 4; ++c)
    qf[c] = *reinterpret_cast<const f16x8*>(qbase + hi * 8 + 16 * c);

  f16x8 ones;
#pragma unroll
  for (int i = 0; i < 8; ++i) ones[i] = (_Float16)1.0f;

  f32x16 O0, O1, lacc;
#pragma unroll
  for (int i = 0; i < 16; ++i) { O0[i] = 0.f; O1[i] = 0.f; lacc[i] = 0.f; }
  float m_q = -3e38f;

  // prologue: stage tile 0 + mask tile 0
  *reinterpret_cast<uint4*>(&Ks[0][so0]) =
      *reinterpret_cast<const uint4*>(kbase + (size_t)r0s * HDc + cs * 8);
  *reinterpret_cast<uint4*>(&Ks[0][so1]) =
      *reinterpret_cast<const uint4*>(kbase + (size_t)r1s * HDc + cs * 8);
  *reinterpret_cast<uint4*>(&Vs[0][so0]) =
      *reinterpret_cast<const uint4*>(vtbase + (size_t)r0s * Sc + cs * 8);
  *reinterpret_cast<uint4*>(&Vs[0][so1]) =
      *reinterpret_cast<const uint4*>(vtbase + (size_t)r1s * Sc + cs * 8);
  float4 mpf[8];
#pragma unroll
  for (int t2 = 0; t2 < 2; ++t2)
#pragma unroll
    for (int j = 0; j < 4; ++j)
      mpf[t2 * 4 + j] = *reinterpret_cast<const float4*>(ml + 32 * t2 + 8 * j);

  for (int kt = 0; kt < NT; ++kt) {
    const int k0 = kt * KB;
    const int cur = kt & 1, nxt = cur ^ 1;
    __syncthreads();

    uint4 kr0, kr1, vr0, vr1;
    const bool pf = (kt + 1) < NT;
    if (pf) {
      const int k1 = k0 + KB;
      kr0 = *reinterpret_cast<const uint4*>(kbase + (size_t)(k1 + r0s) * HDc + cs * 8);
      kr1 = *reinterpret_cast<const uint4*>(kbase + (size_t)(k1 + r1s) * HDc + cs * 8);
      vr0 = *reinterpret_cast<const uint4*>(vtbase + (size_t)r0s * Sc + k1 + cs * 8);
      vr1 = *reinterpret_cast<const uint4*>(vtbase + (size_t)r1s * Sc + k1 + cs * 8);
    }

    // S^T = K Q^T per 32-k half: lane holds q=l31; k = 32*t2 + (reg&3)+8*(reg>>2)+4*hi
    f32x16 s[2];
    __builtin_amdgcn_s_setprio(1);
#pragma unroll
    for (int t2 = 0; t2 < 2; ++t2) {
      f32x16 acc;
#pragma unroll
      for (int i = 0; i < 16; ++i) acc[i] = 0.f;
      const int krow = t2 * 32 + l31;
#pragma unroll
      for (int c = 0; c < 4; ++c) {
        const int ofs = krow * 64 + (((2 * c + hi) ^ (krow & 7)) * 8);
        acc = __builtin_amdgcn_mfma_f32_32x32x16_f16(
            *reinterpret_cast<const f16x8*>(&Ks[cur][ofs]), qf[c], acc, 0, 0, 0);
      }
      s[t2] = acc;
    }
    __builtin_amdgcn_s_setprio(0);

    // + mask (prefetched), then prefetch next tile's mask
#pragma unroll
    for (int t2 = 0; t2 < 2; ++t2)
#pragma unroll
      for (int j = 0; j < 4; ++j) {
        float4 mv = mpf[t2 * 4 + j];
        s[t2][4 * j + 0] += mv.x; s[t2][4 * j + 1] += mv.y;
        s[t2][4 * j + 2] += mv.z; s[t2][4 * j + 3] += mv.w;
      }
    if (pf) {
#pragma unroll
      for (int t2 = 0; t2 < 2; ++t2)
#pragma unroll
        for (int j = 0; j < 4; ++j)
          mpf[t2 * 4 + j] = *reinterpret_cast<const float4*>(
              ml + (k0 + KB) + 32 * t2 + 8 * j);
    }

    // defer-max: per-lane scalar max of this lane's 32 scores
    float lm = s[0][0];
#pragma unroll
    for (int t2 = 0; t2 < 2; ++t2)
#pragma unroll
      for (int i = 0; i < 16; ++i) lm = fmaxf(lm, s[t2][i]);

    if (!__all(lm - m_q <= 8.0f)) {
      // rare: combine the two hi-halves of the row, rescale O/lacc
      float vm = fmaxf(lm, __shfl_xor(lm, 32));
      float mn = fmaxf(m_q, vm);
      float cc = __expf(m_q - mn);
      m_q = mn;
#pragma unroll
      for (int reg = 0; reg < 16; ++reg) {
        int q_r = (reg & 3) + 8 * (reg >> 2) + 4 * hi;
        float ccr = __shfl(cc, q_r);
        O0[reg] *= ccr; O1[reg] *= ccr; lacc[reg] *= ccr;
      }
    }

    // per 16-k chunk: exp -> pack -> permlane swap -> PV + ones MFMA
    __builtin_amdgcn_s_setprio(1);
#pragma unroll
    for (int c = 0; c < 4; ++c) {
      const int t2 = c >> 1, rb = (c & 1) * 8;
      float p0 = __expf(s[t2][rb + 0] - m_q);
      float p1 = __expf(s[t2][rb + 1] - m_q);
      float p2 = __expf(s[t2][rb + 2] - m_q);
      float p3 = __expf(s[t2][rb + 3] - m_q);
      float p4 = __expf(s[t2][rb + 4] - m_q);
      float p5 = __expf(s[t2][rb + 5] - m_q);
      float p6 = __expf(s[t2][rb + 6] - m_q);
      float p7 = __expf(s[t2][rb + 7] - m_q);
      union { fp16v2 h; unsigned int u; } w0, w1, w2, w3;
      w0.h = __builtin_amdgcn_cvt_pkrtz(p0, p1);
      w1.h = __builtin_amdgcn_cvt_pkrtz(p2, p3);
      w2.h = __builtin_amdgcn_cvt_pkrtz(p4, p5);
      w3.h = __builtin_amdgcn_cvt_pkrtz(p6, p7);
      unsigned int u0 = w0.u, u1 = w1.u, u2 = w2.u, u3 = w3.u;
      // dst upper <-> src lower: builds A-frag words for both hi-halves
      asm("v_permlane32_swap_b32 %0, %1" : "+v"(u0), "+v"(u2));
      asm("v_permlane32_swap_b32 %0, %1" : "+v"(u1), "+v"(u3));
      union { unsigned int u[4]; f16x8 f; } pa;
      pa.u[0] = u0; pa.u[1] = u1; pa.u[2] = u2; pa.u[3] = u3;

      lacc = __builtin_amdgcn_mfma_f32_32x32x16_f16(pa.f, ones, lacc, 0, 0, 0);
      const int vofs = l31 * 64 + (((2 * c + hi) ^ (l31 & 7)) * 8);
      O0 = __builtin_amdgcn_mfma_f32_32x32x16_f16(
          pa.f, *reinterpret_cast<const f16x8*>(&Vs[cur][vofs]), O0, 0, 0, 0);
      O1 = __builtin_amdgcn_mfma_f32_32x32x16_f16(
          pa.f, *reinterpret_cast<const f16x8*>(&Vs[cur][vofs + 32 * 64]), O1, 0, 0, 0);
    }
    __builtin_amdgcn_s_setprio(0);

    // land prefetched K/V into buf[nxt]
    if (pf) {
      *reinterpret_cast<uint4*>(&Ks[nxt][so0]) = kr0;
      *reinterpret_cast<uint4*>(&Ks[nxt][so1]) = kr1;
      *reinterpret_cast<uint4*>(&Vs[nxt][so0]) = vr0;
      *reinterpret_cast<uint4*>(&Vs[nxt][so1]) = vr1;
    }
  }

  // epilogue: O/lacc are in the SAME layout -> no cross-lane ops
#pragma unroll
  for (int reg = 0; reg < 16; ++reg) {
    int q_r = (reg & 3) + 8 * (reg >> 2) + 4 * hi;
    float inv = 1.0f / lacc[reg];
    size_t rowbase = ((size_t)b * Sc + (q0 + wq * 32 + q_r)) * Dc + h * HDc;
    ctxh[rowbase + l31]      = (_Float16)(O0[reg] * inv);
    ctxh[rowbase + 32 + l31] = (_Float16)(O1[reg] * inv);
  }
}

// ---------------------------------------------------------------------------
extern "C" void kernel_launch(void* const* d_in, const int* in_sizes, int n_in,
                              void* d_out, int out_size, void* d_ws, size_t ws_size,
                              hipStream_t stream) {
  const float* feats = (const float*)d_in[0];
  const float* mask  = (const float*)d_in[1];
  const float* wq    = (const float*)d_in[2];
  const float* bq    = (const float*)d_in[3];
  const float* wk    = (const float*)d_in[4];
  const float* bk    = (const float*)d_in[5];
  const float* wv    = (const float*)d_in[6];
  const float* bv    = (const float*)d_in[7];
  const float* wo    = (const float*)d_in[8];
  const float* bo    = (const float*)d_in[9];

  char* ws = (char*)d_ws;
  const size_t MB = (size_t)1 << 20;
  _Float16* fh   = (_Float16*)(ws);             // 8 MB
  _Float16* wh3  = (_Float16*)(ws + 8  * MB);   // 6 MB  [wq;wk;wv]
  _Float16* woh  = (_Float16*)(ws + 14 * MB);   // 2 MB
  _Float16* qb   = (_Float16*)(ws + 16 * MB);   // 8 MB
  _Float16* kb   = (_Float16*)(ws + 24 * MB);   // 8 MB
  _Float16* vtb  = (_Float16*)(ws + 32 * MB);   // 8 MB
  _Float16* ctxh = (_Float16*)(ws + 40 * MB);   // 8 MB -> 48 MB total

  float* out   = (float*)d_out;
  float* gated = out + 4194304;

  cvt5<<<8192, 256, 0, stream>>>(feats, wq, wk, wv, wo, fh, wh3, woh);

  gemm_qkv<<<dim3(NROWS / 128, 3072 / 128), 256, 0, stream>>>(
      fh, wh3, bq, bk, bv, qb, kb, vtb);

  attn_mfma<<<Bc * Hc * (Sc / QB), 256, 0, stream>>>(qb, kb, vtb, mask, ctxh);

  gemm_wo<<<dim3(NROWS / 64, Dc / 128), 256, 0, stream>>>(
      ctxh, woh, bo, out, gated, feats);
}

// Round 14
// 150.071 us; speedup vs baseline: 2.2670x; 1.0602x over previous
//
#include <hip/hip_runtime.h>
#include <math.h>

#define Bc 2
#define Sc 2048
#define Dc 1024
#define Hc 16
#define HDc 64
#define NROWS 4096  // B*S

typedef __attribute__((ext_vector_type(8))) _Float16 f16x8;
typedef __attribute__((ext_vector_type(4))) _Float16 f16x4;
typedef __attribute__((ext_vector_type(2))) __fp16 fp16v2;
typedef __attribute__((ext_vector_type(4))) float f32x4;
typedef __attribute__((ext_vector_type(16))) float f32x16;

// ---------------------------------------------------------------------------
// Fused 5-way fp32 -> f16 convert (feats, wq, wk, wv, wo).
// ---------------------------------------------------------------------------
__global__ __launch_bounds__(256)
void cvt5(const float* __restrict__ f,  const float* __restrict__ wq,
          const float* __restrict__ wk, const float* __restrict__ wv,
          const float* __restrict__ wo_,
          _Float16* __restrict__ fh, _Float16* __restrict__ wh3,
          _Float16* __restrict__ woh)
{
  int blk = blockIdx.x;
  const float* src; _Float16* hi; int base;
  if (blk < 4096)      { src = f;   hi = fh;            base = blk; }
  else if (blk < 5120) { src = wq;  hi = wh3;           base = blk - 4096; }
  else if (blk < 6144) { src = wk;  hi = wh3 + 1048576; base = blk - 5120; }
  else if (blk < 7168) { src = wv;  hi = wh3 + 2097152; base = blk - 6144; }
  else                 { src = wo_; hi = woh;           base = blk - 7168; }
  int i = base * 256 + threadIdx.x;
  float4 v = reinterpret_cast<const float4*>(src)[i];
  f16x4 h;
  h[0] = (_Float16)v.x; h[1] = (_Float16)v.y;
  h[2] = (_Float16)v.z; h[3] = (_Float16)v.w;
  reinterpret_cast<f16x4*>(hi)[i] = h;
}

// ---------------------------------------------------------------------------
// Mask scan: flag = 1 if any mask element nonzero. (5 µs; enables fast path)
// ---------------------------------------------------------------------------
__global__ __launch_bounds__(256)
void mask_scan(const float* __restrict__ m, unsigned int* __restrict__ flag)
{
  int i = blockIdx.x * 256 + threadIdx.x;
  float4 v = reinterpret_cast<const float4*>(m)[i];
  bool nz = (v.x != 0.f) || (v.y != 0.f) || (v.z != 0.f) || (v.w != 0.f);
  if (__any(nz)) {
    if ((threadIdx.x & 63) == 0) atomicOr(flag, 1u);
  }
}

// ---------------------------------------------------------------------------
// Fused QKV f16 GEMM (unchanged).
// ---------------------------------------------------------------------------
__global__ __launch_bounds__(256, 4)
void gemm_qkv(const _Float16* __restrict__ Ah, const _Float16* __restrict__ Wh,
              const float* __restrict__ bq, const float* __restrict__ bk,
              const float* __restrict__ bv,
              _Float16* __restrict__ qb, _Float16* __restrict__ kb,
              _Float16* __restrict__ vtb)
{
  __shared__ _Float16 Ash[128][40];
  __shared__ _Float16 Wsh[128][40];

  const int tid  = threadIdx.x;
  const int lane = tid & 63, wid = tid >> 6;
  const int l15  = lane & 15, l4 = lane >> 4;
  const int wr   = wid >> 1, wc = wid & 1;
  const int arow0 = blockIdx.x * 128;
  const int wrow0 = blockIdx.y * 128;

  f32x4 acc[4][4];
#pragma unroll
  for (int m = 0; m < 4; ++m)
#pragma unroll
    for (int n = 0; n < 4; ++n) acc[m][n] = f32x4{0.f, 0.f, 0.f, 0.f};

  for (int k0 = 0; k0 < Dc; k0 += 32) {
    __syncthreads();
#pragma unroll
    for (int p = 0; p < 2; ++p) {
      int e = tid + 256 * p;
      int r = e >> 2, c8 = (e & 3) * 8;
      *reinterpret_cast<uint4*>(&Ash[r][c8]) =
          *reinterpret_cast<const uint4*>(Ah + (size_t)(arow0 + r) * Dc + k0 + c8);
      *reinterpret_cast<uint4*>(&Wsh[r][c8]) =
          *reinterpret_cast<const uint4*>(Wh + (size_t)(wrow0 + r) * Dc + k0 + c8);
    }
    __syncthreads();

    f16x8 bh[4];
#pragma unroll
    for (int n = 0; n < 4; ++n)
      bh[n] = *reinterpret_cast<const f16x8*>(&Wsh[wc * 64 + n * 16 + l15][l4 * 8]);
#pragma unroll
    for (int m = 0; m < 4; ++m) {
      f16x8 ah = *reinterpret_cast<const f16x8*>(&Ash[wr * 64 + m * 16 + l15][l4 * 8]);
#pragma unroll
      for (int n = 0; n < 4; ++n)
        acc[m][n] = __builtin_amdgcn_mfma_f32_16x16x32_f16(ah, bh[n], acc[m][n], 0, 0, 0);
    }
  }

#pragma unroll
  for (int m = 0; m < 4; ++m) {
#pragma unroll
    for (int n = 0; n < 4; ++n) {
      int cbase = wrow0 + wc * 64 + n * 16;
      int seg = cbase >> 10;
      int o = (cbase & 1023) + l15;
      int h = o >> 6, hd = o & 63;
      const float* bias = (seg == 0) ? bq : ((seg == 1) ? bk : bv);
      float bval = bias[o];
      float alpha = (seg == 0) ? 0.125f : 1.0f;
      int r0 = arow0 + wr * 64 + m * 16 + l4 * 4;
      int b = r0 >> 11, s0 = r0 & (Sc - 1);
      if (seg == 2) {
        f16x4 pk;
#pragma unroll
        for (int reg = 0; reg < 4; ++reg)
          pk[reg] = (_Float16)((acc[m][n][reg] + bval) * alpha);
        *reinterpret_cast<f16x4*>(
            &vtb[(((size_t)b * Hc + h) * HDc + hd) * Sc + s0]) = pk;
      } else {
        _Float16* dst = (seg == 0) ? qb : kb;
#pragma unroll
        for (int reg = 0; reg < 4; ++reg) {
          float val = (acc[m][n][reg] + bval) * alpha;
          dst[(((size_t)b * Hc + h) * Sc + (s0 + reg)) * HDc + hd] = (_Float16)val;
        }
      }
    }
  }
}

// ---------------------------------------------------------------------------
// Output GEMM (unchanged).
// ---------------------------------------------------------------------------
__global__ __launch_bounds__(256, 4)
void gemm_wo(const _Float16* __restrict__ Ah, const _Float16* __restrict__ Wh,
             const float* __restrict__ bias,
             float* __restrict__ out0, float* __restrict__ out1,
             const float* __restrict__ feats)
{
  __shared__ _Float16 Ash[64][40];
  __shared__ _Float16 Wsh[128][40];

  const int tid  = threadIdx.x;
  const int lane = tid & 63, wid = tid >> 6;
  const int l15  = lane & 15, l4 = lane >> 4;
  const int wr   = wid >> 1, wc = wid & 1;
  const int arow0 = blockIdx.x * 64;
  const int wrow0 = blockIdx.y * 128;

  f32x4 acc[2][4];
#pragma unroll
  for (int m = 0; m < 2; ++m)
#pragma unroll
    for (int n = 0; n < 4; ++n) acc[m][n] = f32x4{0.f, 0.f, 0.f, 0.f};

  for (int k0 = 0; k0 < Dc; k0 += 32) {
    __syncthreads();
    {
      int r = tid >> 2, c8 = (tid & 3) * 8;
      *reinterpret_cast<uint4*>(&Ash[r][c8]) =
          *reinterpret_cast<const uint4*>(Ah + (size_t)(arow0 + r) * Dc + k0 + c8);
    }
#pragma unroll
    for (int p = 0; p < 2; ++p) {
      int e = tid + 256 * p;
      int r = e >> 2, c8 = (e & 3) * 8;
      *reinterpret_cast<uint4*>(&Wsh[r][c8]) =
          *reinterpret_cast<const uint4*>(Wh + (size_t)(wrow0 + r) * Dc + k0 + c8);
    }
    __syncthreads();

    f16x8 bh[4];
#pragma unroll
    for (int n = 0; n < 4; ++n)
      bh[n] = *reinterpret_cast<const f16x8*>(&Wsh[wc * 64 + n * 16 + l15][l4 * 8]);
#pragma unroll
    for (int m = 0; m < 2; ++m) {
      f16x8 ah = *reinterpret_cast<const f16x8*>(&Ash[wr * 32 + m * 16 + l15][l4 * 8]);
#pragma unroll
      for (int n = 0; n < 4; ++n)
        acc[m][n] = __builtin_amdgcn_mfma_f32_16x16x32_f16(ah, bh[n], acc[m][n], 0, 0, 0);
    }
  }

#pragma unroll
  for (int m = 0; m < 2; ++m) {
#pragma unroll
    for (int n = 0; n < 4; ++n) {
      int c = wrow0 + wc * 64 + n * 16 + l15;
      float bval = bias[c];
#pragma unroll
      for (int reg = 0; reg < 4; ++reg) {
        int r = arow0 + wr * 32 + m * 16 + l4 * 4 + reg;
        float val = acc[m][n][reg] + bval;
        out1[(size_t)r * Dc + c] = val;
        out0[(size_t)r * Dc + c] = feats[(size_t)r * Dc + c] * val;
      }
    }
  }
}

// ---------------------------------------------------------------------------
// Flash attention, 32x32x16 f16 MFMA (round-13 structure) +
// (a) zero-mask fast path (uniform branch on device flag),
// (b) XCD-chunked block swizzle: each XCD gets 4 whole heads -> KV L2-resident.
// ---------------------------------------------------------------------------
#define QB 128
#define KB 64
#define NT (Sc / KB)

__global__ __launch_bounds__(256, 2)
void attn_mfma(const _Float16* __restrict__ q,
               const _Float16* __restrict__ k,
               const _Float16* __restrict__ vt,
               const float* __restrict__ mask,
               const unsigned int* __restrict__ mflag,
               _Float16* __restrict__ ctxh)
{
  __shared__ _Float16 Ks[2][KB * 64];        // [k-row][hd], XOR-swizzled
  __shared__ _Float16 Vs[2][HDc * 64];       // V^T [d][k], XOR-swizzled

  const int tid  = threadIdx.x;
  const int lane = tid & 63;
  const int wq   = tid >> 6;                 // wave 0..3
  const int l31  = lane & 31;
  const int hi   = lane >> 5;

  const int nqb  = Sc / QB;                  // 16; grid = 512 = 8 XCD x 64
  const int bid  = blockIdx.x;
  const int swz  = (bid & 7) * 64 + (bid >> 3);   // XCD-chunked, bijective
  const int head = swz / nqb;
  const int q0   = (swz % nqb) * QB;
  const int b    = head / Hc;
  const int h    = head % Hc;

  const bool use_mask = (*mflag != 0u);

  const _Float16* kbase  = k  + (size_t)head * Sc * HDc;
  const _Float16* vtbase = vt + (size_t)head * HDc * Sc;
  const _Float16* qbase  = q  + ((size_t)head * Sc + q0 + wq * 32 + l31) * HDc;
  const float*    ml     = mask + ((size_t)b * Sc + q0 + wq * 32 + l31) * Sc + 4 * hi;

  const int r0s = tid >> 3, cs = tid & 7;
  const int r1s = r0s + 32;
  const int so0 = r0s * 64 + ((cs ^ (r0s & 7)) * 8);
  const int so1 = r1s * 64 + ((cs ^ (r1s & 7)) * 8);

  f16x8 qf[4];
#pragma unroll
  for (int c = 0; c < 4; ++c)
    qf[c] = *reinterpret_cast<const f16x8*>(qbase + hi * 8 + 16 * c);

  f16x8 ones;
#pragma unroll
  for (int i = 0; i < 8; ++i) ones[i] = (_Float16)1.0f;

  f32x16 O0, O1, lacc;
#pragma unroll
  for (int i = 0; i < 16; ++i) { O0[i] = 0.f; O1[i] = 0.f; lacc[i] = 0.f; }
  float m_q = -3e38f;

  *reinterpret_cast<uint4*>(&Ks[0][so0]) =
      *reinterpret_cast<const uint4*>(kbase + (size_t)r0s * HDc + cs * 8);
  *reinterpret_cast<uint4*>(&Ks[0][so1]) =
      *reinterpret_cast<const uint4*>(kbase + (size_t)r1s * HDc + cs * 8);
  *reinterpret_cast<uint4*>(&Vs[0][so0]) =
      *reinterpret_cast<const uint4*>(vtbase + (size_t)r0s * Sc + cs * 8);
  *reinterpret_cast<uint4*>(&Vs[0][so1]) =
      *reinterpret_cast<const uint4*>(vtbase + (size_t)r1s * Sc + cs * 8);
  float4 mpf[8];
  if (use_mask) {
#pragma unroll
    for (int t2 = 0; t2 < 2; ++t2)
#pragma unroll
      for (int j = 0; j < 4; ++j)
        mpf[t2 * 4 + j] = *reinterpret_cast<const float4*>(ml + 32 * t2 + 8 * j);
  }

  for (int kt = 0; kt < NT; ++kt) {
    const int k0 = kt * KB;
    const int cur = kt & 1, nxt = cur ^ 1;
    __syncthreads();

    uint4 kr0, kr1, vr0, vr1;
    const bool pf = (kt + 1) < NT;
    if (pf) {
      const int k1 = k0 + KB;
      kr0 = *reinterpret_cast<const uint4*>(kbase + (size_t)(k1 + r0s) * HDc + cs * 8);
      kr1 = *reinterpret_cast<const uint4*>(kbase + (size_t)(k1 + r1s) * HDc + cs * 8);
      vr0 = *reinterpret_cast<const uint4*>(vtbase + (size_t)r0s * Sc + k1 + cs * 8);
      vr1 = *reinterpret_cast<const uint4*>(vtbase + (size_t)r1s * Sc + k1 + cs * 8);
    }

    f32x16 s[2];
    __builtin_amdgcn_s_setprio(1);
#pragma unroll
    for (int t2 = 0; t2 < 2; ++t2) {
      f32x16 acc;
#pragma unroll
      for (int i = 0; i < 16; ++i) acc[i] = 0.f;
      const int krow = t2 * 32 + l31;
#pragma unroll
      for (int c = 0; c < 4; ++c) {
        const int ofs = krow * 64 + (((2 * c + hi) ^ (krow & 7)) * 8);
        acc = __builtin_amdgcn_mfma_f32_32x32x16_f16(
            *reinterpret_cast<const f16x8*>(&Ks[cur][ofs]), qf[c], acc, 0, 0, 0);
      }
      s[t2] = acc;
    }
    __builtin_amdgcn_s_setprio(0);

    if (use_mask) {
#pragma unroll
      for (int t2 = 0; t2 < 2; ++t2)
#pragma unroll
        for (int j = 0; j < 4; ++j) {
          float4 mv = mpf[t2 * 4 + j];
          s[t2][4 * j + 0] += mv.x; s[t2][4 * j + 1] += mv.y;
          s[t2][4 * j + 2] += mv.z; s[t2][4 * j + 3] += mv.w;
        }
      if (pf) {
#pragma unroll
        for (int t2 = 0; t2 < 2; ++t2)
#pragma unroll
          for (int j = 0; j < 4; ++j)
            mpf[t2 * 4 + j] = *reinterpret_cast<const float4*>(
                ml + (k0 + KB) + 32 * t2 + 8 * j);
      }
    }

    float lm = s[0][0];
#pragma unroll
    for (int t2 = 0; t2 < 2; ++t2)
#pragma unroll
      for (int i = 0; i < 16; ++i) lm = fmaxf(lm, s[t2][i]);

    if (!__all(lm - m_q <= 8.0f)) {
      float vm = fmaxf(lm, __shfl_xor(lm, 32));
      float mn = fmaxf(m_q, vm);
      float cc = __expf(m_q - mn);
      m_q = mn;
#pragma unroll
      for (int reg = 0; reg < 16; ++reg) {
        int q_r = (reg & 3) + 8 * (reg >> 2) + 4 * hi;
        float ccr = __shfl(cc, q_r);
        O0[reg] *= ccr; O1[reg] *= ccr; lacc[reg] *= ccr;
      }
    }

    __builtin_amdgcn_s_setprio(1);
#pragma unroll
    for (int c = 0; c < 4; ++c) {
      const int t2 = c >> 1, rb = (c & 1) * 8;
      float p0 = __expf(s[t2][rb + 0] - m_q);
      float p1 = __expf(s[t2][rb + 1] - m_q);
      float p2 = __expf(s[t2][rb + 2] - m_q);
      float p3 = __expf(s[t2][rb + 3] - m_q);
      float p4 = __expf(s[t2][rb + 4] - m_q);
      float p5 = __expf(s[t2][rb + 5] - m_q);
      float p6 = __expf(s[t2][rb + 6] - m_q);
      float p7 = __expf(s[t2][rb + 7] - m_q);
      union { fp16v2 h; unsigned int u; } w0, w1, w2, w3;
      w0.h = __builtin_amdgcn_cvt_pkrtz(p0, p1);
      w1.h = __builtin_amdgcn_cvt_pkrtz(p2, p3);
      w2.h = __builtin_amdgcn_cvt_pkrtz(p4, p5);
      w3.h = __builtin_amdgcn_cvt_pkrtz(p6, p7);
      unsigned int u0 = w0.u, u1 = w1.u, u2 = w2.u, u3 = w3.u;
      asm("v_permlane32_swap_b32 %0, %1" : "+v"(u0), "+v"(u2));
      asm("v_permlane32_swap_b32 %0, %1" : "+v"(u1), "+v"(u3));
      union { unsigned int u[4]; f16x8 f; } pa;
      pa.u[0] = u0; pa.u[1] = u1; pa.u[2] = u2; pa.u[3] = u3;

      lacc = __builtin_amdgcn_mfma_f32_32x32x16_f16(pa.f, ones, lacc, 0, 0, 0);
      const int vofs = l31 * 64 + (((2 * c + hi) ^ (l31 & 7)) * 8);
      O0 = __builtin_amdgcn_mfma_f32_32x32x16_f16(
          pa.f, *reinterpret_cast<const f16x8*>(&Vs[cur][vofs]), O0, 0, 0, 0);
      O1 = __builtin_amdgcn_mfma_f32_32x32x16_f16(
          pa.f, *reinterpret_cast<const f16x8*>(&Vs[cur][vofs + 32 * 64]), O1, 0, 0, 0);
    }
    __builtin_amdgcn_s_setprio(0);

    if (pf) {
      *reinterpret_cast<uint4*>(&Ks[nxt][so0]) = kr0;
      *reinterpret_cast<uint4*>(&Ks[nxt][so1]) = kr1;
      *reinterpret_cast<uint4*>(&Vs[nxt][so0]) = vr0;
      *reinterpret_cast<uint4*>(&Vs[nxt][so1]) = vr1;
    }
  }

#pragma unroll
  for (int reg = 0; reg < 16; ++reg) {
    int q_r = (reg & 3) + 8 * (reg >> 2) + 4 * hi;
    float inv = 1.0f / lacc[reg];
    size_t rowbase = ((size_t)b * Sc + (q0 + wq * 32 + q_r)) * Dc + h * HDc;
    ctxh[rowbase + l31]      = (_Float16)(O0[reg] * inv);
    ctxh[rowbase + 32 + l31] = (_Float16)(O1[reg] * inv);
  }
}

// ---------------------------------------------------------------------------
extern "C" void kernel_launch(void* const* d_in, const int* in_sizes, int n_in,
                              void* d_out, int out_size, void* d_ws, size_t ws_size,
                              hipStream_t stream) {
  const float* feats = (const float*)d_in[0];
  const float* mask  = (const float*)d_in[1];
  const float* wq    = (const float*)d_in[2];
  const float* bq    = (const float*)d_in[3];
  const float* wk    = (const float*)d_in[4];
  const float* bk    = (const float*)d_in[5];
  const float* wv    = (const float*)d_in[6];
  const float* bv    = (const float*)d_in[7];
  const float* wo    = (const float*)d_in[8];
  const float* bo    = (const float*)d_in[9];

  char* ws = (char*)d_ws;
  const size_t MB = (size_t)1 << 20;
  _Float16* fh    = (_Float16*)(ws);             // 8 MB
  _Float16* wh3   = (_Float16*)(ws + 8  * MB);   // 6 MB
  _Float16* woh   = (_Float16*)(ws + 14 * MB);   // 2 MB
  _Float16* qb    = (_Float16*)(ws + 16 * MB);   // 8 MB
  _Float16* kb    = (_Float16*)(ws + 24 * MB);   // 8 MB
  _Float16* vtb   = (_Float16*)(ws + 32 * MB);   // 8 MB
  _Float16* ctxh  = (_Float16*)(ws + 40 * MB);   // 8 MB
  unsigned int* mflag = (unsigned int*)(ws + 48 * MB);

  float* out   = (float*)d_out;
  float* gated = out + 4194304;

  hipMemsetAsync(mflag, 0, 4, stream);
  mask_scan<<<8192, 256, 0, stream>>>(mask, mflag);

  cvt5<<<8192, 256, 0, stream>>>(feats, wq, wk, wv, wo, fh, wh3, woh);

  gemm_qkv<<<dim3(NROWS / 128, 3072 / 128), 256, 0, stream>>>(
      fh, wh3, bq, bk, bv, qb, kb, vtb);

  attn_mfma<<<Bc * Hc * (Sc / QB), 256, 0, stream>>>(qb, kb, vtb, mask, mflag, ctxh);

  gemm_wo<<<dim3(NROWS / 64, Dc / 128), 256, 0, stream>>>(
      ctxh, woh, bo, out, gated, feats);
}